// Round 8
// baseline (466.865 us; speedup 1.0000x reference)
//
#include <hip/hip_runtime.h>
#include <math.h>

// Problem constants
#define NN 2048
#define MM 16
#define DD 512
#define DE 128
#define HH 8
#define GG 50
#define DH 64
#define DEH 16

typedef __attribute__((ext_vector_type(8))) short bf8_t;   // 8 bf16 = 4 VGPRs
typedef __attribute__((ext_vector_type(4))) float f4_t;    // MFMA accumulator
typedef unsigned short us;

// Async global->LDS 16B copy. LDS dest must be wave-uniform base; HW writes
// base + lane*16. Global src is per-lane.
__device__ __forceinline__ void gload16(const us* g, us* l) {
    __builtin_amdgcn_global_load_lds(
        (const __attribute__((address_space(1))) unsigned int*)g,
        (__attribute__((address_space(3))) unsigned int*)l, 16, 0, 0);
}

// Branchless tanh-approx GELU (max |err| vs erf-gelu ~3e-3, fine for bf16 out)
__device__ __forceinline__ float gelu_f(float x) {
    float u = 1.5957691216f * fmaf(0.044715f * x, x * x, x);
    u = fminf(fmaxf(u, -30.f), 30.f);
    float e = __expf(u);
    float t = fmaf(-2.f, __builtin_amdgcn_rcpf(e + 1.f), 1.f);  // tanh(u/2)
    float hx = 0.5f * x;
    return fmaf(hx, t, hx);
}

__device__ __forceinline__ float wsum(float v) {
#pragma unroll
    for (int o = 32; o; o >>= 1) v += __shfl_xor(v, o, 64);
    return v;
}

__device__ __forceinline__ us f2bf(float x) {
    union { float f; unsigned int u; } v;
    v.f = x;
    unsigned int r = v.u + 0x7FFFu + ((v.u >> 16) & 1u);  // RNE
    return (us)(r >> 16);
}

__device__ __forceinline__ float bfu(unsigned int u) {
    union { unsigned int x; float f; } v;
    v.x = u;
    return v.f;
}
#define BF_LO(u) bfu((u) << 16)
#define BF_HI(u) bfu((u) & 0xFFFF0000u)
__device__ __forceinline__ float b2f(us u) { return bfu((unsigned int)u << 16); }

// ---------------------------------------------------------------------------
// Row-wise (optional GELU) + LayerNorm. Writes fp32 and/or bf16 output.
// ---------------------------------------------------------------------------
__global__ __launch_bounds__(256) void act_ln_kernel(float* __restrict__ outF,
                                                     us* __restrict__ outB,
                                                     const float* __restrict__ x,
                                                     int C, int do_gelu) {
    int row = blockIdx.x, tid = threadIdx.x;
    int nv = C >> 8;  // C is 512 or 2048
    float v[8];
    float s = 0.f, ss = 0.f;
    for (int i = 0; i < nv; ++i) {
        float val = x[(size_t)row * C + tid + (i << 8)];
        if (do_gelu) val = gelu_f(val);
        v[i] = val;
        s += val;
        ss += val * val;
    }
    __shared__ float red[4][2];
    s = wsum(s);
    ss = wsum(ss);
    int wid = tid >> 6, lane = tid & 63;
    if (lane == 0) { red[wid][0] = s; red[wid][1] = ss; }
    __syncthreads();
    s = red[0][0] + red[1][0] + red[2][0] + red[3][0];
    ss = red[0][1] + red[1][1] + red[2][1] + red[3][1];
    float mean = s / (float)C;
    float var = ss / (float)C - mean * mean;
    float rs = rsqrtf(var + 1e-5f);
    for (int i = 0; i < nv; ++i) {
        float y = (v[i] - mean) * rs;
        size_t idx = (size_t)row * C + tid + (i << 8);
        if (outF) outF[idx] = y;
        if (outB) outB[idx] = f2bf(y);
    }
}

// ---------------------------------------------------------------------------
// Fused transpose-casts: W [K,N] fp32 -> Wt [N,K] bf16, 9 jobs in one launch.
// ---------------------------------------------------------------------------
struct TCJob {
    const float* src;
    us* dst;
    int K, N, b0;
};
struct TC9 {
    TCJob j[9];
};

__global__ __launch_bounds__(256) void tcast_all(TC9 P) {
    __shared__ float tile[32][33];
    int b = blockIdx.x;
    int ji = 0;
#pragma unroll
    for (int i = 1; i < 9; ++i)
        if (b >= P.j[i].b0) ji = i;
    const float* W = P.j[ji].src;
    us* Wt = P.j[ji].dst;
    int K = P.j[ji].K, N = P.j[ji].N;
    int lb = b - P.j[ji].b0;
    int nbx = (N + 31) >> 5;
    int n0 = (lb % nbx) * 32, k0 = (lb / nbx) * 32;
    int tx = threadIdx.x & 31, ty = threadIdx.x >> 5;
#pragma unroll
    for (int p = 0; p < 4; ++p) {
        int k = k0 + ty + p * 8;
        tile[ty + p * 8][tx] = (k < K && n0 + tx < N) ? W[(size_t)k * N + n0 + tx] : 0.f;
    }
    __syncthreads();
#pragma unroll
    for (int p = 0; p < 4; ++p) {
        int n = n0 + ty + p * 8;
        if (n < N && k0 + tx < K) Wt[(size_t)n * K + k0 + tx] = f2bf(tile[tx][ty + p * 8]);
    }
}

// ---------------------------------------------------------------------------
// wesT[c][t] = wa1[128+t][c] for t<16 else 0   -> bf16 [512, 32]
// ---------------------------------------------------------------------------
__global__ __launch_bounds__(256) void wesT_kernel(const float* __restrict__ wa1,
                                                   us* __restrict__ wesT) {
    int idx = blockIdx.x * 256 + threadIdx.x;  // < 512*32
    int c = idx >> 5, t = idx & 31;
    wesT[idx] = (t < 16) ? f2bf(wa1[(size_t)(128 + t) * 512 + c]) : (us)0;
}

// ---------------------------------------------------------------------------
// bf16 MFMA GEMM: out = A[M,K](bf16) @ Bt[N,K](bf16)^T (+bias[col])
//                 (+resid[M,N] fp32) (+residH[M/8,N] fp32, row-broadcast by 8)
// 128x128 tile, 4 waves (2x2). K-step 64. Staging via global_load_lds with
// pre-swizzled per-lane SOURCE addresses (LDS dest linear per wave).
// Requires: 128|M, 128|N, 64|K.
// ---------------------------------------------------------------------------
__global__ __launch_bounds__(256) void gemm_bf16_kernel(
    const us* __restrict__ A, const us* __restrict__ Bt,
    const float* __restrict__ bias, const float* __restrict__ resid,
    const float* __restrict__ residH,
    float* __restrict__ outF, us* __restrict__ outB,
    int M, int K, int N) {
    __shared__ us As[128 * 64];
    __shared__ us Bs[128 * 64];
    int tid = threadIdx.x;
    int lane = tid & 63;
    int w = tid >> 6;
    int wr = w >> 1, wc = w & 1;
    int row0 = blockIdx.y * 128, col0 = blockIdx.x * 128;
    f4_t acc[4][4];
#pragma unroll
    for (int a = 0; a < 4; ++a)
#pragma unroll
        for (int b = 0; b < 4; ++b) {
            acc[a][b][0] = 0.f; acc[a][b][1] = 0.f;
            acc[a][b][2] = 0.f; acc[a][b][3] = 0.f;
        }

    for (int kt = 0; kt < K; kt += 64) {
        __syncthreads();  // prior compute done before overwrite
#pragma unroll
        for (int p = 0; p < 4; ++p) {
            int id = p * 256 + tid;        // 1024 chunks of 16B
            int r = id >> 3, cch = id & 7;
            int kc = cch ^ (r & 7);        // swizzled source chunk
            int wb = p * 256 + (tid & 192);  // wave-uniform LDS chunk base
            gload16(A + (size_t)(row0 + r) * K + kt + kc * 8, As + wb * 8);
            gload16(Bt + (size_t)(col0 + r) * K + kt + kc * 8, Bs + wb * 8);
        }
        __syncthreads();  // drains vmcnt then barrier
#pragma unroll
        for (int kk = 0; kk < 2; ++kk) {
            bf8_t af[4], bfr[4];
            int kslot = kk * 4 + (lane >> 4);
#pragma unroll
            for (int mi = 0; mi < 4; ++mi) {
                int r = wr * 64 + mi * 16 + (lane & 15);
                af[mi] = *(const bf8_t*)((char*)As + r * 128 + ((kslot ^ (r & 7)) * 16));
            }
#pragma unroll
            for (int ni = 0; ni < 4; ++ni) {
                int r = wc * 64 + ni * 16 + (lane & 15);
                bfr[ni] = *(const bf8_t*)((char*)Bs + r * 128 + ((kslot ^ (r & 7)) * 16));
            }
#pragma unroll
            for (int mi = 0; mi < 4; ++mi)
#pragma unroll
                for (int ni = 0; ni < 4; ++ni)
                    acc[mi][ni] = __builtin_amdgcn_mfma_f32_16x16x32_bf16(
                        af[mi], bfr[ni], acc[mi][ni], 0, 0, 0);
        }
    }
    int cr = lane >> 4, cc = lane & 15;
#pragma unroll
    for (int mi = 0; mi < 4; ++mi)
#pragma unroll
        for (int ni = 0; ni < 4; ++ni) {
            int col = col0 + wc * 64 + ni * 16 + cc;
            float bv = bias ? bias[col] : 0.f;
#pragma unroll
            for (int j = 0; j < 4; ++j) {
                int row = row0 + wr * 64 + mi * 16 + cr * 4 + j;
                float v = acc[mi][ni][j] + bv;
                if (resid) v += resid[(size_t)row * N + col];
                if (residH) v += residH[(size_t)(row >> 3) * N + col];
                if (outF) outF[(size_t)row * N + col] = v;
                if (outB) outB[(size_t)row * N + col] = f2bf(v);
            }
        }
}

// ---------------------------------------------------------------------------
// Generic fp32 GEMM (K=50 / N=50 cases): C = A@W (+bias), fp32/bf16 out.
// ---------------------------------------------------------------------------
__global__ __launch_bounds__(256) void gemm_kernel(const float* __restrict__ A,
                                                   const float* __restrict__ W,
                                                   const float* __restrict__ bias,
                                                   float* __restrict__ outF,
                                                   us* __restrict__ outB,
                                                   int Mr, int K, int Nc) {
    __shared__ float Ast[16][68];
    __shared__ float Ws[16][68];
    int tid = threadIdx.x;
    int tx = tid & 15, ty = tid >> 4;
    int row0 = blockIdx.y << 6, col0 = blockIdx.x << 6;
    int r0 = ty << 2, c0 = tx << 2;
    float acc[4][4] = {};
    for (int k0 = 0; k0 < K; k0 += 16) {
#pragma unroll
        for (int i = 0; i < 4; ++i) {
            int idx = tid + (i << 8);
            int r = idx >> 4, kk = idx & 15;
            int gr = row0 + r, gk = k0 + kk;
            Ast[kk][r] = (gr < Mr && gk < K) ? A[(size_t)gr * K + gk] : 0.f;
            int kw = idx >> 6, c = idx & 63;
            int gc = col0 + c, gkw = k0 + kw;
            Ws[kw][c] = (gkw < K && gc < Nc) ? W[(size_t)gkw * Nc + gc] : 0.f;
        }
        __syncthreads();
#pragma unroll
        for (int kk = 0; kk < 16; ++kk) {
            float4 a4 = *(const float4*)&Ast[kk][r0];
            float4 b4 = *(const float4*)&Ws[kk][c0];
            float av[4] = {a4.x, a4.y, a4.z, a4.w};
            float bv[4] = {b4.x, b4.y, b4.z, b4.w};
#pragma unroll
            for (int i = 0; i < 4; ++i)
#pragma unroll
                for (int j = 0; j < 4; ++j) acc[i][j] = fmaf(av[i], bv[j], acc[i][j]);
        }
        __syncthreads();
    }
#pragma unroll
    for (int i = 0; i < 4; ++i) {
        int r = row0 + r0 + i;
        if (r >= Mr) continue;
#pragma unroll
        for (int j = 0; j < 4; ++j) {
            int c = col0 + c0 + j;
            if (c >= Nc) continue;
            float v = acc[i][j];
            if (bias) v += bias[c];
            if (outF) outF[(size_t)r * Nc + c] = v;
            if (outB) outB[(size_t)r * Nc + c] = f2bf(v);
        }
    }
}

// ---------------------------------------------------------------------------
// Repack q,k heads from qkv bf16 [N,1536] into bf16 [N*H, 64]. 4 elems/thread.
// ---------------------------------------------------------------------------
__global__ __launch_bounds__(256) void repack_qk(const us* __restrict__ qkv,
                                                 us* __restrict__ q2,
                                                 us* __restrict__ k2) {
    int idx = blockIdx.x * 256 + threadIdx.x;  // < 16384*16
    int r = idx >> 4, t4 = (idx & 15) << 2;
    int n = r >> 3, h = r & 7;
    *(uint2*)(q2 + (size_t)r * 64 + t4) = *(const uint2*)(qkv + (size_t)n * 1536 + h * 64 + t4);
    *(uint2*)(k2 + (size_t)r * 64 + t4) =
        *(const uint2*)(qkv + (size_t)n * 1536 + 512 + h * 64 + t4);
}

// ---------------------------------------------------------------------------
// Frame projections: per (n,m) PCA-frame projection + radial norm.
// ---------------------------------------------------------------------------
__global__ __launch_bounds__(256) void proj_kernel(const float* __restrict__ coords,
                                                   const int* __restrict__ nbr,
                                                   float* __restrict__ projs,
                                                   float* __restrict__ rns) {
    int node = blockIdx.x * 16 + (threadIdx.x >> 4);
    int m = threadIdx.x & 15;
    float cx = coords[node * 2], cy = coords[node * 2 + 1];
    int j = nbr[node * 16 + m];
    float rx = coords[j * 2] - cx;
    float ry = coords[j * 2 + 1] - cy;
    float rn = sqrtf(rx * rx + ry * ry);
    float mx = rx, my = ry;
#pragma unroll
    for (int o = 8; o; o >>= 1) { mx += __shfl_xor(mx, o, 16); my += __shfl_xor(my, o, 16); }
    mx *= 0.0625f;
    my *= 0.0625f;
    float xcx = rx - mx, xcy = ry - my;
    float sxx = xcx * xcx, sxy = xcx * xcy, syy = xcy * xcy;
#pragma unroll
    for (int o = 8; o; o >>= 1) {
        sxx += __shfl_xor(sxx, o, 16);
        sxy += __shfl_xor(sxy, o, 16);
        syy += __shfl_xor(syy, o, 16);
    }
    double a = (double)sxx, b = (double)sxy, c = (double)syy;
    double diff = 0.5 * (a - c);
    double disc = sqrt(diff * diff + b * b);
    double l2 = 0.5 * (a + c) + disc;
    double v2x = b, v2y = l2 - a;
    double nn2 = sqrt(v2x * v2x + v2y * v2y);
    if (nn2 < 1e-30) { v2x = (a >= c) ? 1.0 : 0.0; v2y = 1.0 - v2x; nn2 = 1.0; }
    v2x /= nn2;
    v2y /= nn2;
    double v1x = -v2y, v1y = v2x;  // eigenvector of smaller eigenvalue
    int row = node * 16 + m;
    projs[row * 2] = (float)((double)xcx * v1x + (double)xcy * v1y);
    projs[row * 2 + 1] = (float)((double)xcx * v2x + (double)xcy * v2y);
    rns[row] = rn;
}

// ---------------------------------------------------------------------------
// Frame MLP stage 1 -> u bf16: u[row,c] = 0.25*sum_f LN(gelu([frame,rn]@we1+be1))
// ---------------------------------------------------------------------------
__global__ __launch_bounds__(256) void frame_mlp1_kernel(const float* __restrict__ projs,
                                                         const float* __restrict__ rns,
                                                         const float* __restrict__ we1,
                                                         const float* __restrict__ be1,
                                                         us* __restrict__ u) {
    int row = blockIdx.x * 4 + (threadIdx.x >> 6);
    int lane = threadIdx.x & 63;
    float px = projs[row * 2], py = projs[row * 2 + 1], rn = rns[row];
    int c0 = lane, c1 = lane + 64;
    float w10a = we1[c0], w11a = we1[128 + c0], w12a = we1[256 + c0], b1a = be1[c0];
    float w10b = we1[c1], w11b = we1[128 + c1], w12b = we1[256 + c1], b1b = be1[c1];
    float acc0 = 0.f, acc1 = 0.f;
    const float opsx[4] = {-1.f, -1.f, 1.f, 1.f};
    const float opsy[4] = {-1.f, 1.f, -1.f, 1.f};
#pragma unroll
    for (int f = 0; f < 4; ++f) {
        float fx = opsx[f] * px, fy = opsy[f] * py;
        float h0 = gelu_f(fmaf(fx, w10a, fmaf(fy, w11a, fmaf(rn, w12a, b1a))));
        float h1 = gelu_f(fmaf(fx, w10b, fmaf(fy, w11b, fmaf(rn, w12b, b1b))));
        float s = wsum(h0 + h1);
        float ss = wsum(fmaf(h0, h0, h1 * h1));
        float mean = s * (1.f / 128.f);
        float var = ss * (1.f / 128.f) - mean * mean;
        float rs = rsqrtf(var + 1e-5f);
        acc0 += (h0 - mean) * rs;
        acc1 += (h1 - mean) * rs;
    }
    u[(size_t)row * 128 + c0] = f2bf(0.25f * acc0);
    u[(size_t)row * 128 + c1] = f2bf(0.25f * acc1);
}

// ---------------------------------------------------------------------------
// Fused logits, transposed MFMA form (see R7). This round:
//  - Wls2 layout [kslot=4][ch=512][8] -> fragment-read banks cc*4%32 = 2-way
//    (free), staged via global_load_lds.
//  - qmg = (qp+ba1) - gep[n] folded at stage time (bf16), deleting the gepn
//    read + 4 unpacks + 4 subs per ct-iteration.
// ---------------------------------------------------------------------------
__global__ __launch_bounds__(256) void logits_fused_kernel(
    const us* __restrict__ qpb,    // qp+ba1 bf16 [16384,512]
    const us* __restrict__ kg,     // kp+gep bf16 [16384,512]
    const us* __restrict__ gepb,   // bf16 [2048,512]
    const us* __restrict__ edgeb,  // bf16 [2048][16][128] (+32 pad at end)
    const us* __restrict__ wesT,   // bf16 [512,32], k=16..31 zero
    const int* __restrict__ nbr,
    const float* __restrict__ wa2,
    const float* __restrict__ ba2,
    float* __restrict__ logits) {
    __shared__ us Wls2[4 * 512 * 8];  // 32 KB: [kslot][ch][8], conflict-free
    __shared__ us Es[2048 + 32];      // 4.2 KB: edge rows (m*8+h) x 16, 32B stride
    __shared__ us qmg[8 * 520];       // 8.1 KB: (qp+ba1-gep[n]) bf16, padded rows
    __shared__ float wa2s[512];       // 2 KB
    __shared__ int jns[16];
    int n = blockIdx.x, tid = threadIdx.x;
    int lane = tid & 63, w = tid >> 6;
    // sw = sum(wa2), redundantly per wave (pre-sync)
    float swv = 0.f;
#pragma unroll
    for (int i = 0; i < 8; ++i) swv += wa2[lane + 64 * i];
    float sw = wsum(swv);
    float ba2v = ba2[0];
    // stage
    {
        // Wls2[cr][ch][0..8] <- wesT[ch*32 + cr*8 ..] via async 16B copies
#pragma unroll
        for (int p = 0; p < 8; ++p) {
            int id = p * 256 + tid;  // 2048 chunks of 16B
            int crq = id >> 9, ch = id & 511;
            int wb = p * 256 + (tid & 192);
            gload16(wesT + ch * 32 + crq * 8, Wls2 + wb * 8);
        }
        const uint* s2 = (const uint*)(edgeb + (size_t)n * 2048);
        uint* d2 = (uint*)Es;
        for (int i = tid; i < 1040; i += 256) d2[i] = s2[i];
        const uint* s3 = (const uint*)(qpb + (size_t)n * 4096);
        const uint* s4 = (const uint*)(gepb + (size_t)n * 512);
        uint* d3 = (uint*)qmg;
        for (int i = tid; i < 2048; i += 256) {
            uint q = s3[i], g = s4[i & 255];
            float lo = BF_LO(q) - BF_LO(g), hi = BF_HI(q) - BF_HI(g);
            d3[(i >> 8) * 260 + (i & 255)] = ((uint)f2bf(hi) << 16) | (uint)f2bf(lo);
        }
        for (int i = tid; i < 512; i += 256) wa2s[i] = wa2[i];
        if (tid < 16) jns[tid] = nbr[n * 16 + tid];
    }
    __syncthreads();

    int cc = lane & 15, cr = lane >> 4;
#pragma unroll
    for (int mt = 0; mt < 2; ++mt) {
        int mh = w * 32 + mt * 16 + cc;
        int m = mh >> 3, h = mh & 7;
        int j8h = jns[m] * 8 + h;
        const us* kgrow = kg + (size_t)j8h * 512;
        const us* qrow = qmg + h * 520;
        // B-operand fragment: edge row mh, k-slot cr (cr>=2 over-reads next
        // row's data which multiplies the zero wesT k=16..31 -> benign)
        bf8_t bfr = *(const bf8_t*)((const char*)Es + mh * 32 + cr * 16);
        float s = 0.f, ss = 0.f, sd = 0.f;
#pragma unroll 4
        for (int ct = 0; ct < 32; ++ct) {
            int chb = ct * 16 + cr * 4;  // this lane's 4 channels
            bf8_t af = *(const bf8_t*)((const char*)Wls2 + (cr * 512 + ct * 16 + cc) * 16);
            f4_t z = {0.f, 0.f, 0.f, 0.f};
            f4_t ep = __builtin_amdgcn_mfma_f32_16x16x32_bf16(af, bfr, z, 0, 0, 0);
            uint2 kg4 = *(const uint2*)(kgrow + chb);
            uint2 qp4 = *(const uint2*)(qrow + chb);
            float4 w4 = *(const float4*)(wa2s + chb);
            float vals[4];
            vals[0] = ep[0] + BF_LO(qp4.x) + BF_LO(kg4.x);
            vals[1] = ep[1] + BF_HI(qp4.x) + BF_HI(kg4.x);
            vals[2] = ep[2] + BF_LO(qp4.y) + BF_LO(kg4.y);
            vals[3] = ep[3] + BF_HI(qp4.y) + BF_HI(kg4.y);
            float wv[4] = {w4.x, w4.y, w4.z, w4.w};
#pragma unroll
            for (int j = 0; j < 4; ++j) {
                float g = gelu_f(vals[j]);
                s += g;
                ss = fmaf(g, g, ss);
                sd = fmaf(g, wv[j], sd);
            }
        }
        // reduce across the 4 cr groups (lanes 16/32 apart), cc preserved
        s += __shfl_xor(s, 16, 64);
        s += __shfl_xor(s, 32, 64);
        ss += __shfl_xor(ss, 16, 64);
        ss += __shfl_xor(ss, 32, 64);
        sd += __shfl_xor(sd, 16, 64);
        sd += __shfl_xor(sd, 32, 64);
        if (cr == 0) {
            float mean = s * (1.f / 512.f);
            float var = ss * (1.f / 512.f) - mean * mean;
            logits[((size_t)n * 8 + h) * 16 + m] =
                (sd - mean * sw) * rsqrtf(var + 1e-5f) + ba2v;
        }
    }
}

// ---------------------------------------------------------------------------
// Softmax over M per (n,h) + context aggregation -> scec bf16 [N,640]
// ---------------------------------------------------------------------------
__global__ __launch_bounds__(256) void smax_agg_kernel(const float* __restrict__ logits,
                                                       const us* __restrict__ qkv,
                                                       const us* __restrict__ edge,
                                                       const int* __restrict__ nbr,
                                                       us* __restrict__ scec) {
    __shared__ float attn[128];
    __shared__ int jn[16];
    int n = blockIdx.x, tid = threadIdx.x;
    if (tid < 16) jn[tid] = nbr[n * 16 + tid];
    if (tid < 128) {
        float lg = logits[(size_t)n * 128 + tid];
        float mx = lg;
#pragma unroll
        for (int o = 8; o; o >>= 1) mx = fmaxf(mx, __shfl_xor(mx, o, 16));
        float e = expf(lg - mx);
        float se = e;
#pragma unroll
        for (int o = 8; o; o >>= 1) se += __shfl_xor(se, o, 16);
        attn[tid] = e / se;
    }
    __syncthreads();
    for (int c = tid; c < 640; c += 256) {
        float acc = 0.f;
        if (c < 512) {
            int h = c >> 6, t = c & 63;
#pragma unroll
            for (int m = 0; m < 16; ++m) {
                us kv = qkv[(size_t)jn[m] * 1536 + 1024 + h * 64 + t];
                acc = fmaf(attn[h * 16 + m], b2f(kv), acc);
            }
        } else {
            int d = c - 512, h = d >> 4, t = d & 15;
#pragma unroll
            for (int m = 0; m < 16; ++m) {
                us ev = edge[((size_t)n * 16 + m) * 128 + h * 16 + t];
                acc = fmaf(attn[h * 16 + m], b2f(ev), acc);
            }
        }
        scec[(size_t)n * 640 + c] = f2bf(acc);
    }
}

// ---------------------------------------------------------------------------
extern "C" void kernel_launch(void* const* d_in, const int* in_sizes, int n_in,
                              void* d_out, int out_size, void* d_ws, size_t ws_size,
                              hipStream_t stream) {
    const float* gene_exp = (const float*)d_in[0];
    const float* token_embs = (const float*)d_in[1];
    const float* coords = (const float*)d_in[2];
    const int* nbr = (const int*)d_in[3];
    const float* w_qkv = (const float*)d_in[4];
    const float* b_qkv = (const float*)d_in[5];
    const float* wa1 = (const float*)d_in[6];
    const float* ba1 = (const float*)d_in[7];
    const float* wa2 = (const float*)d_in[8];
    const float* ba2 = (const float*)d_in[9];
    const float* we1 = (const float*)d_in[10];
    const float* be1 = (const float*)d_in[11];
    const float* we2 = (const float*)d_in[12];
    const float* be2 = (const float*)d_in[13];
    const float* wo1 = (const float*)d_in[14];
    const float* bo1 = (const float*)d_in[15];
    const float* wo2 = (const float*)d_in[16];
    const float* bo2 = (const float*)d_in[17];
    const float* wm1 = (const float*)d_in[18];
    const float* bm1 = (const float*)d_in[19];
    const float* wm2 = (const float*)d_in[20];
    const float* bm2 = (const float*)d_in[21];
    const float* wg1 = (const float*)d_in[22];
    const float* bg1 = (const float*)d_in[23];
    const float* wg2 = (const float*)d_in[24];
    const float* bg2 = (const float*)d_in[25];

    float* out = (float*)d_out;
    float* gene_out = out;             // [2048, 50]
    float* tok_out = out + 2048 * 50;  // [2048, 512]

    float* ws = (float*)d_ws;
    size_t o = 0;
    auto alloc = [&](size_t nf) {
        float* p = ws + o;
        o += nf;
        return p;
    };
    us* x_ln_bf = (us*)alloc((size_t)2048 * 512 / 2);
    us* qkv_bf = (us*)alloc((size_t)2048 * 1536 / 2);
    us* q2b = (us*)alloc((size_t)16384 * 64 / 2);
    us* k2b = (us*)alloc((size_t)16384 * 64 / 2);
    us* qpb = (us*)alloc((size_t)16384 * 512 / 2);
    us* kgb = (us*)alloc((size_t)16384 * 512 / 2);
    float* gep = alloc((size_t)2048 * 512);
    us* gepb = (us*)alloc((size_t)2048 * 512 / 2);
    us* edgeb = (us*)alloc(((size_t)2048 * 2048 + 32) / 2);
    float* logitsb = alloc((size_t)2048 * 128);
    us* scec_bf = (us*)alloc((size_t)2048 * 640 / 2);
    float* buf1 = alloc((size_t)2048 * 512);
    us* buf1_bf = (us*)alloc((size_t)2048 * 512 / 2);
    float* buf2 = alloc((size_t)2048 * 2048);
    us* buf2_bf = (us*)alloc((size_t)2048 * 2048 / 2);
    float* tok1 = alloc((size_t)2048 * 512);
    us* tok1_bf = (us*)alloc((size_t)2048 * 512 / 2);
    us* tokout_bf = (us*)alloc((size_t)2048 * 512 / 2);
    us* u_bf = (us*)alloc((size_t)32768 * 128 / 2);
    float* projs = alloc((size_t)32768 * 2);
    float* rns = alloc((size_t)32768);
    us* qkvT = (us*)alloc((size_t)1536 * 512 / 2);
    us* wa1qT = (us*)alloc((size_t)512 * 64 / 2);
    us* wa1kT = (us*)alloc((size_t)512 * 64 / 2);
    us* we2T = (us*)alloc((size_t)128 * 128 / 2);
    us* wo1T = (us*)alloc((size_t)512 * 640 / 2);
    us* wo2T = (us*)alloc((size_t)512 * 512 / 2);
    us* wm1T = (us*)alloc((size_t)2048 * 512 / 2);
    us* wm2T = (us*)alloc((size_t)512 * 2048 / 2);
    us* wg1T = (us*)alloc((size_t)512 * 512 / 2);
    us* wesT = (us*)alloc((size_t)512 * 32 / 2);
    if (o * sizeof(float) > ws_size) return;  // ~122 MB required

    auto G = [&](const us* A, const us* Bt, const float* bias, const float* resid,
                 const float* residH, float* outF, us* outB, int M, int K, int N) {
        gemm_bf16_kernel<<<dim3(N / 128, M / 128), 256, 0, stream>>>(
            A, Bt, bias, resid, residH, outF, outB, M, K, N);
    };

    // 0. fused weight transpose-casts + wesT
    {
        TC9 P;
        auto set = [&](int i, const float* s, us* d, int K, int N, int& acc) {
            P.j[i] = {s, d, K, N, acc};
            acc += ((N + 31) / 32) * ((K + 31) / 32);
        };
        int acc = 0;
        set(0, w_qkv, qkvT, 512, 1536, acc);
        set(1, wa1, wa1qT, 64, 512, acc);
        set(2, wa1 + 64 * 512, wa1kT, 64, 512, acc);
        set(3, we2, we2T, 128, 128, acc);
        set(4, wo1, wo1T, 640, 512, acc);
        set(5, wo2, wo2T, 512, 512, acc);
        set(6, wm1, wm1T, 512, 2048, acc);
        set(7, wm2, wm2T, 2048, 512, acc);
        set(8, wg1, wg1T, 512, 512, acc);
        tcast_all<<<acc, 256, 0, stream>>>(P);
        wesT_kernel<<<64, 256, 0, stream>>>(wa1, wesT);
    }

    // 1. x_ln_bf = LN(token_embs) (bf16)
    act_ln_kernel<<<2048, 256, 0, stream>>>(nullptr, x_ln_bf, token_embs, 512, 0);
    // 2. qkv = x_ln @ w_qkv + b_qkv (bf16)
    G(x_ln_bf, qkvT, b_qkv, nullptr, nullptr, nullptr, qkv_bf, 2048, 512, 1536);
    // 3. repack q,k -> bf16 [16384,64]
    repack_qk<<<1024, 256, 0, stream>>>(qkv_bf, q2b, k2b);
    // 4. gene fc1 piece (K=50, fp32 kernel) -> gep fp32 + gepb bf16 (before kg)
    gemm_kernel<<<dim3(8, 32), 256, 0, stream>>>(gene_exp, wa1 + 144 * 512, nullptr,
                                                 gep, gepb, 2048, 50, 512);
    // 5. qpb = q@wa1_q + ba1 (bf16); kg = k@wa1_k + gep[row>>3] (bf16)
    G(q2b, wa1qT, ba1, nullptr, nullptr, nullptr, qpb, 16384, 64, 512);
    G(k2b, wa1kT, nullptr, nullptr, gep, nullptr, kgb, 16384, 64, 512);
    // 6. frame-averaged edge features -> edgeb bf16 (incl. be2)
    proj_kernel<<<128, 256, 0, stream>>>(coords, nbr, projs, rns);
    frame_mlp1_kernel<<<8192, 256, 0, stream>>>(projs, rns, we1, be1, u_bf);
    G(u_bf, we2T, be2, nullptr, nullptr, nullptr, edgeb, 32768, 128, 128);
    // 7. fused logits (transposed MFMA edge term + assemble + gelu + LN-dot)
    logits_fused_kernel<<<2048, 256, 0, stream>>>(qpb, kgb, gepb, edgeb, wesT, nbr, wa2,
                                                  ba2, logitsb);
    // 8. softmax + context aggregation -> scec bf16
    smax_agg_kernel<<<2048, 256, 0, stream>>>(logitsb, qkv_bf, edgeb, nbr, scec_bf);
    // 9. ctx = mlp2(scec, wo1, wo2); tok1 = token_embs + ctx
    G(scec_bf, wo1T, bo1, nullptr, nullptr, buf1, nullptr, 2048, 640, 512);
    act_ln_kernel<<<2048, 256, 0, stream>>>(nullptr, buf1_bf, buf1, 512, 1);
    G(buf1_bf, wo2T, bo2, token_embs, nullptr, tok1, tok1_bf, 2048, 512, 512);
    // 10. tok2 = tok1 + mlp2(tok1, wm1, wm2) -> d_out tok section
    G(tok1_bf, wm1T, bm1, nullptr, nullptr, buf2, nullptr, 2048, 512, 2048);
    act_ln_kernel<<<2048, 256, 0, stream>>>(nullptr, buf2_bf, buf2, 2048, 1);
    G(buf2_bf, wm2T, bm2, tok1, nullptr, tok_out, tokout_bf, 2048, 2048, 512);
    // 11. gene_out = mlp2(tok2, wg1, wg2)
    G(tokout_bf, wg1T, bg1, nullptr, nullptr, buf1, nullptr, 2048, 512, 512);
    act_ln_kernel<<<2048, 256, 0, stream>>>(buf1, nullptr, buf1, 512, 1);
    gemm_kernel<<<dim3(1, 32), 256, 0, stream>>>(buf1, wg2, bg2, gene_out, nullptr,
                                                 2048, 512, 50);
}

// Round 9
// 423.173 us; speedup vs baseline: 1.1032x; 1.1032x over previous
//
#include <hip/hip_runtime.h>
#include <math.h>

// Problem constants
#define NN 2048
#define MM 16
#define DD 512
#define DE 128
#define HH 8
#define GG 50
#define DH 64
#define DEH 16

typedef __attribute__((ext_vector_type(8))) short bf8_t;   // 8 bf16 = 4 VGPRs
typedef __attribute__((ext_vector_type(4))) float f4_t;    // MFMA accumulator
typedef unsigned short us;

// Async global->LDS 16B copy. LDS dest must be wave-uniform base; HW writes
// base + lane*16. Global src is per-lane.
__device__ __forceinline__ void gload16(const us* g, us* l) {
    __builtin_amdgcn_global_load_lds(
        (const __attribute__((address_space(1))) unsigned int*)g,
        (__attribute__((address_space(3))) unsigned int*)l, 16, 0, 0);
}

// Branchless tanh-approx GELU (max |err| vs erf-gelu ~3e-3, fine for bf16 out)
__device__ __forceinline__ float gelu_f(float x) {
    float u = 1.5957691216f * fmaf(0.044715f * x, x * x, x);
    u = fminf(fmaxf(u, -30.f), 30.f);
    float e = __expf(u);
    float t = fmaf(-2.f, __builtin_amdgcn_rcpf(e + 1.f), 1.f);  // tanh(u/2)
    float hx = 0.5f * x;
    return fmaf(hx, t, hx);
}

__device__ __forceinline__ float wsum(float v) {
#pragma unroll
    for (int o = 32; o; o >>= 1) v += __shfl_xor(v, o, 64);
    return v;
}

__device__ __forceinline__ us f2bf(float x) {
    union { float f; unsigned int u; } v;
    v.f = x;
    unsigned int r = v.u + 0x7FFFu + ((v.u >> 16) & 1u);  // RNE
    return (us)(r >> 16);
}

__device__ __forceinline__ float bfu(unsigned int u) {
    union { unsigned int x; float f; } v;
    v.x = u;
    return v.f;
}
#define BF_LO(u) bfu((u) << 16)
#define BF_HI(u) bfu((u) & 0xFFFF0000u)
__device__ __forceinline__ float b2f(us u) { return bfu((unsigned int)u << 16); }

// ---------------------------------------------------------------------------
// Row-wise (optional GELU) + LayerNorm. Writes fp32 and/or bf16 output.
// ---------------------------------------------------------------------------
__global__ __launch_bounds__(256) void act_ln_kernel(float* __restrict__ outF,
                                                     us* __restrict__ outB,
                                                     const float* __restrict__ x,
                                                     int C, int do_gelu) {
    int row = blockIdx.x, tid = threadIdx.x;
    int nv = C >> 8;  // C is 512 or 2048
    float v[8];
    float s = 0.f, ss = 0.f;
    for (int i = 0; i < nv; ++i) {
        float val = x[(size_t)row * C + tid + (i << 8)];
        if (do_gelu) val = gelu_f(val);
        v[i] = val;
        s += val;
        ss += val * val;
    }
    __shared__ float red[4][2];
    s = wsum(s);
    ss = wsum(ss);
    int wid = tid >> 6, lane = tid & 63;
    if (lane == 0) { red[wid][0] = s; red[wid][1] = ss; }
    __syncthreads();
    s = red[0][0] + red[1][0] + red[2][0] + red[3][0];
    ss = red[0][1] + red[1][1] + red[2][1] + red[3][1];
    float mean = s / (float)C;
    float var = ss / (float)C - mean * mean;
    float rs = rsqrtf(var + 1e-5f);
    for (int i = 0; i < nv; ++i) {
        float y = (v[i] - mean) * rs;
        size_t idx = (size_t)row * C + tid + (i << 8);
        if (outF) outF[idx] = y;
        if (outB) outB[idx] = f2bf(y);
    }
}

// ---------------------------------------------------------------------------
// Fused transpose-casts: W [K,N] fp32 -> Wt [N,Kld] bf16 (zero-fill K..Kld),
// 11 jobs in one launch.
// ---------------------------------------------------------------------------
struct TCJob {
    const float* src;
    us* dst;
    int K, N, Kld, b0;
};
struct TC11 {
    TCJob j[11];
};

__global__ __launch_bounds__(256) void tcast_all(TC11 P) {
    __shared__ float tile[32][33];
    int b = blockIdx.x;
    int ji = 0;
#pragma unroll
    for (int i = 1; i < 11; ++i)
        if (b >= P.j[i].b0) ji = i;
    const float* W = P.j[ji].src;
    us* Wt = P.j[ji].dst;
    int K = P.j[ji].K, N = P.j[ji].N, Kld = P.j[ji].Kld;
    int lb = b - P.j[ji].b0;
    int nbx = (N + 31) >> 5;
    int n0 = (lb % nbx) * 32, k0 = (lb / nbx) * 32;
    int tx = threadIdx.x & 31, ty = threadIdx.x >> 5;
#pragma unroll
    for (int p = 0; p < 4; ++p) {
        int k = k0 + ty + p * 8;
        tile[ty + p * 8][tx] = (k < K && n0 + tx < N) ? W[(size_t)k * N + n0 + tx] : 0.f;
    }
    __syncthreads();
#pragma unroll
    for (int p = 0; p < 4; ++p) {
        int n = n0 + ty + p * 8;
        if (n < N && k0 + tx < Kld) Wt[(size_t)n * Kld + k0 + tx] = f2bf(tile[tx][ty + p * 8]);
    }
}

// ---------------------------------------------------------------------------
// wesT[c][t] = wa1[128+t][c] for t<16 else 0   -> bf16 [512, 32]
// ---------------------------------------------------------------------------
__global__ __launch_bounds__(256) void wesT_kernel(const float* __restrict__ wa1,
                                                   us* __restrict__ wesT) {
    int idx = blockIdx.x * 256 + threadIdx.x;  // < 512*32
    int c = idx >> 5, t = idx & 31;
    wesT[idx] = (t < 16) ? f2bf(wa1[(size_t)(128 + t) * 512 + c]) : (us)0;
}

// ---------------------------------------------------------------------------
// gene_bf[r][c] = bf16(gene_exp[r][c]) for c<50 else 0  -> [2048, 64]
// ---------------------------------------------------------------------------
__global__ __launch_bounds__(256) void gene_cast_kernel(const float* __restrict__ g,
                                                        us* __restrict__ out) {
    int idx = blockIdx.x * 256 + threadIdx.x;  // < 2048*64
    int r = idx >> 6, c = idx & 63;
    out[idx] = (c < 50) ? f2bf(g[r * 50 + c]) : (us)0;
}

// ---------------------------------------------------------------------------
// bf16 MFMA GEMM: out = A[M,K](bf16) @ Bt[N,K](bf16)^T (+bias[col])
//                 (+resid[M,Nout] fp32) (+residH[M/8,Nout] fp32, row-bcast 8)
// 128x128 tile, 4 waves (2x2). K-step 64. Double-buffered LDS with prefetch:
// STAGE(t+1) issued BEFORE compute(t); one barrier/step drains it (T3-min).
// Staging via global_load_lds, pre-swizzled per-lane source addresses.
// Requires: 128|M, 128|N, 64|K. Output guarded/strided by Nout (<=N).
// ---------------------------------------------------------------------------
__global__ __launch_bounds__(256) void gemm_bf16_kernel(
    const us* __restrict__ A, const us* __restrict__ Bt,
    const float* __restrict__ bias, const float* __restrict__ resid,
    const float* __restrict__ residH,
    float* __restrict__ outF, us* __restrict__ outB,
    int M, int K, int N, int Nout) {
    __shared__ us As[2][128 * 64];
    __shared__ us Bs[2][128 * 64];
    int tid = threadIdx.x;
    int lane = tid & 63;
    int w = tid >> 6;
    int wr = w >> 1, wc = w & 1;
    int row0 = blockIdx.y * 128, col0 = blockIdx.x * 128;
    f4_t acc[4][4];
#pragma unroll
    for (int a = 0; a < 4; ++a)
#pragma unroll
        for (int b = 0; b < 4; ++b) {
            acc[a][b][0] = 0.f; acc[a][b][1] = 0.f;
            acc[a][b][2] = 0.f; acc[a][b][3] = 0.f;
        }

    auto stage = [&](int buf, int kt) {
#pragma unroll
        for (int p = 0; p < 4; ++p) {
            int id = p * 256 + tid;          // 1024 chunks of 16B
            int r = id >> 3, cch = id & 7;
            int kc = cch ^ (r & 7);          // swizzled source chunk
            int wb = p * 256 + (tid & 192);  // wave-uniform LDS chunk base
            gload16(A + (size_t)(row0 + r) * K + kt + kc * 8, As[buf] + wb * 8);
            gload16(Bt + (size_t)(col0 + r) * K + kt + kc * 8, Bs[buf] + wb * 8);
        }
    };

    int nkt = K >> 6;
    stage(0, 0);
    __syncthreads();  // drain prologue loads
    for (int t = 0; t < nkt; ++t) {
        int cur = t & 1;
        if (t + 1 < nkt) stage(cur ^ 1, (t + 1) << 6);  // prefetch next tile
#pragma unroll
        for (int kk = 0; kk < 2; ++kk) {
            bf8_t af[4], bfr[4];
            int kslot = kk * 4 + (lane >> 4);
#pragma unroll
            for (int mi = 0; mi < 4; ++mi) {
                int r = wr * 64 + mi * 16 + (lane & 15);
                af[mi] = *(const bf8_t*)((char*)As[cur] + r * 128 + ((kslot ^ (r & 7)) * 16));
            }
#pragma unroll
            for (int ni = 0; ni < 4; ++ni) {
                int r = wc * 64 + ni * 16 + (lane & 15);
                bfr[ni] = *(const bf8_t*)((char*)Bs[cur] + r * 128 + ((kslot ^ (r & 7)) * 16));
            }
#pragma unroll
            for (int mi = 0; mi < 4; ++mi)
#pragma unroll
                for (int ni = 0; ni < 4; ++ni)
                    acc[mi][ni] = __builtin_amdgcn_mfma_f32_16x16x32_bf16(
                        af[mi], bfr[ni], acc[mi][ni], 0, 0, 0);
        }
        __syncthreads();  // drains prefetch (vmcnt0) + protects buffer reuse
    }
    int cr = lane >> 4, cc = lane & 15;
#pragma unroll
    for (int mi = 0; mi < 4; ++mi)
#pragma unroll
        for (int ni = 0; ni < 4; ++ni) {
            int col = col0 + wc * 64 + ni * 16 + cc;
            if (col >= Nout) continue;
            float bv = bias ? bias[col] : 0.f;
#pragma unroll
            for (int j = 0; j < 4; ++j) {
                int row = row0 + wr * 64 + mi * 16 + cr * 4 + j;
                float v = acc[mi][ni][j] + bv;
                if (resid) v += resid[(size_t)row * Nout + col];
                if (residH) v += residH[(size_t)(row >> 3) * Nout + col];
                if (outF) outF[(size_t)row * Nout + col] = v;
                if (outB) outB[(size_t)row * Nout + col] = f2bf(v);
            }
        }
}

// ---------------------------------------------------------------------------
// Repack q,k heads from qkv bf16 [N,1536] into bf16 [N*H, 64]. 4 elems/thread.
// ---------------------------------------------------------------------------
__global__ __launch_bounds__(256) void repack_qk(const us* __restrict__ qkv,
                                                 us* __restrict__ q2,
                                                 us* __restrict__ k2) {
    int idx = blockIdx.x * 256 + threadIdx.x;  // < 16384*16
    int r = idx >> 4, t4 = (idx & 15) << 2;
    int n = r >> 3, h = r & 7;
    *(uint2*)(q2 + (size_t)r * 64 + t4) = *(const uint2*)(qkv + (size_t)n * 1536 + h * 64 + t4);
    *(uint2*)(k2 + (size_t)r * 64 + t4) =
        *(const uint2*)(qkv + (size_t)n * 1536 + 512 + h * 64 + t4);
}

// ---------------------------------------------------------------------------
// Frame projections: per (n,m) PCA-frame projection + radial norm.
// ---------------------------------------------------------------------------
__global__ __launch_bounds__(256) void proj_kernel(const float* __restrict__ coords,
                                                   const int* __restrict__ nbr,
                                                   float* __restrict__ projs,
                                                   float* __restrict__ rns) {
    int node = blockIdx.x * 16 + (threadIdx.x >> 4);
    int m = threadIdx.x & 15;
    float cx = coords[node * 2], cy = coords[node * 2 + 1];
    int j = nbr[node * 16 + m];
    float rx = coords[j * 2] - cx;
    float ry = coords[j * 2 + 1] - cy;
    float rn = sqrtf(rx * rx + ry * ry);
    float mx = rx, my = ry;
#pragma unroll
    for (int o = 8; o; o >>= 1) { mx += __shfl_xor(mx, o, 16); my += __shfl_xor(my, o, 16); }
    mx *= 0.0625f;
    my *= 0.0625f;
    float xcx = rx - mx, xcy = ry - my;
    float sxx = xcx * xcx, sxy = xcx * xcy, syy = xcy * xcy;
#pragma unroll
    for (int o = 8; o; o >>= 1) {
        sxx += __shfl_xor(sxx, o, 16);
        sxy += __shfl_xor(sxy, o, 16);
        syy += __shfl_xor(syy, o, 16);
    }
    double a = (double)sxx, b = (double)sxy, c = (double)syy;
    double diff = 0.5 * (a - c);
    double disc = sqrt(diff * diff + b * b);
    double l2 = 0.5 * (a + c) + disc;
    double v2x = b, v2y = l2 - a;
    double nn2 = sqrt(v2x * v2x + v2y * v2y);
    if (nn2 < 1e-30) { v2x = (a >= c) ? 1.0 : 0.0; v2y = 1.0 - v2x; nn2 = 1.0; }
    v2x /= nn2;
    v2y /= nn2;
    double v1x = -v2y, v1y = v2x;  // eigenvector of smaller eigenvalue
    int row = node * 16 + m;
    projs[row * 2] = (float)((double)xcx * v1x + (double)xcy * v1y);
    projs[row * 2 + 1] = (float)((double)xcx * v2x + (double)xcy * v2y);
    rns[row] = rn;
}

// ---------------------------------------------------------------------------
// Frame MLP stage 1 -> u bf16: u[row,c] = 0.25*sum_f LN(gelu([frame,rn]@we1+be1))
// ---------------------------------------------------------------------------
__global__ __launch_bounds__(256) void frame_mlp1_kernel(const float* __restrict__ projs,
                                                         const float* __restrict__ rns,
                                                         const float* __restrict__ we1,
                                                         const float* __restrict__ be1,
                                                         us* __restrict__ u) {
    int row = blockIdx.x * 4 + (threadIdx.x >> 6);
    int lane = threadIdx.x & 63;
    float px = projs[row * 2], py = projs[row * 2 + 1], rn = rns[row];
    int c0 = lane, c1 = lane + 64;
    float w10a = we1[c0], w11a = we1[128 + c0], w12a = we1[256 + c0], b1a = be1[c0];
    float w10b = we1[c1], w11b = we1[128 + c1], w12b = we1[256 + c1], b1b = be1[c1];
    float acc0 = 0.f, acc1 = 0.f;
    const float opsx[4] = {-1.f, -1.f, 1.f, 1.f};
    const float opsy[4] = {-1.f, 1.f, -1.f, 1.f};
#pragma unroll
    for (int f = 0; f < 4; ++f) {
        float fx = opsx[f] * px, fy = opsy[f] * py;
        float h0 = gelu_f(fmaf(fx, w10a, fmaf(fy, w11a, fmaf(rn, w12a, b1a))));
        float h1 = gelu_f(fmaf(fx, w10b, fmaf(fy, w11b, fmaf(rn, w12b, b1b))));
        float s = wsum(h0 + h1);
        float ss = wsum(fmaf(h0, h0, h1 * h1));
        float mean = s * (1.f / 128.f);
        float var = ss * (1.f / 128.f) - mean * mean;
        float rs = rsqrtf(var + 1e-5f);
        acc0 += (h0 - mean) * rs;
        acc1 += (h1 - mean) * rs;
    }
    u[(size_t)row * 128 + c0] = f2bf(0.25f * acc0);
    u[(size_t)row * 128 + c1] = f2bf(0.25f * acc1);
}

// ---------------------------------------------------------------------------
// Fused logits, transposed MFMA form (see R7). This round: wesT fragments
// read directly from global (L2-hot 32KB shared by all blocks) -> LDS drops
// to ~15KB -> ~8 blocks/CU for latency hiding over the kg gathers.
// ---------------------------------------------------------------------------
__global__ __launch_bounds__(256) void logits_fused_kernel(
    const us* __restrict__ qpb,    // qp+ba1 bf16 [16384,512]
    const us* __restrict__ kg,     // kp+gep bf16 [16384,512]
    const us* __restrict__ gepb,   // bf16 [2048,512]
    const us* __restrict__ edgeb,  // bf16 [2048][16][128] (+32 pad at end)
    const us* __restrict__ wesT,   // bf16 [512,32], k=16..31 zero
    const int* __restrict__ nbr,
    const float* __restrict__ wa2,
    const float* __restrict__ ba2,
    float* __restrict__ logits) {
    __shared__ us Es[2048 + 32];  // 4.2 KB: edge rows (m*8+h) x 16, 32B stride
    __shared__ us qmg[8 * 520];   // 8.1 KB: (qp+ba1-gep[n]) bf16, padded rows
    __shared__ float wa2s[512];   // 2 KB
    __shared__ int jns[16];
    int n = blockIdx.x, tid = threadIdx.x;
    int lane = tid & 63;
    // sw = sum(wa2), redundantly per wave (pre-sync)
    float swv = 0.f;
#pragma unroll
    for (int i = 0; i < 8; ++i) swv += wa2[lane + 64 * i];
    float sw = wsum(swv);
    float ba2v = ba2[0];
    // stage
    {
        const uint* s2 = (const uint*)(edgeb + (size_t)n * 2048);
        uint* d2 = (uint*)Es;
        for (int i = tid; i < 1040; i += 256) d2[i] = s2[i];
        const uint* s3 = (const uint*)(qpb + (size_t)n * 4096);
        const uint* s4 = (const uint*)(gepb + (size_t)n * 512);
        uint* d3 = (uint*)qmg;
        for (int i = tid; i < 2048; i += 256) {
            uint q = s3[i], g = s4[i & 255];
            float lo = BF_LO(q) - BF_LO(g), hi = BF_HI(q) - BF_HI(g);
            d3[(i >> 8) * 260 + (i & 255)] = ((uint)f2bf(hi) << 16) | (uint)f2bf(lo);
        }
        for (int i = tid; i < 512; i += 256) wa2s[i] = wa2[i];
        if (tid < 16) jns[tid] = nbr[n * 16 + tid];
    }
    __syncthreads();

    int cc = lane & 15, cr = lane >> 4;
    int w = tid >> 6;
#pragma unroll
    for (int mt = 0; mt < 2; ++mt) {
        int mh = w * 32 + mt * 16 + cc;
        int m = mh >> 3, h = mh & 7;
        int j8h = jns[m] * 8 + h;
        const us* kgrow = kg + (size_t)j8h * 512;
        const us* qrow = qmg + h * 520;
        // B-operand fragment: edge row mh, k-slot cr (cr>=2 over-reads next
        // row's data which multiplies the zero wesT k=16..31 -> benign)
        bf8_t bfr = *(const bf8_t*)((const char*)Es + mh * 32 + cr * 16);
        float s = 0.f, ss = 0.f, sd = 0.f;
#pragma unroll 4
        for (int ct = 0; ct < 32; ++ct) {
            int chb = ct * 16 + cr * 4;  // this lane's 4 channels
            bf8_t af = *(const bf8_t*)(wesT + (ct * 16 + cc) * 32 + cr * 8);
            f4_t z = {0.f, 0.f, 0.f, 0.f};
            f4_t ep = __builtin_amdgcn_mfma_f32_16x16x32_bf16(af, bfr, z, 0, 0, 0);
            uint2 kg4 = *(const uint2*)(kgrow + chb);
            uint2 qp4 = *(const uint2*)(qrow + chb);
            float4 w4 = *(const float4*)(wa2s + chb);
            float vals[4];
            vals[0] = ep[0] + BF_LO(qp4.x) + BF_LO(kg4.x);
            vals[1] = ep[1] + BF_HI(qp4.x) + BF_HI(kg4.x);
            vals[2] = ep[2] + BF_LO(qp4.y) + BF_LO(kg4.y);
            vals[3] = ep[3] + BF_HI(qp4.y) + BF_HI(kg4.y);
            float wv[4] = {w4.x, w4.y, w4.z, w4.w};
#pragma unroll
            for (int j = 0; j < 4; ++j) {
                float g = gelu_f(vals[j]);
                s += g;
                ss = fmaf(g, g, ss);
                sd = fmaf(g, wv[j], sd);
            }
        }
        // reduce across the 4 cr groups (lanes 16/32 apart), cc preserved
        s += __shfl_xor(s, 16, 64);
        s += __shfl_xor(s, 32, 64);
        ss += __shfl_xor(ss, 16, 64);
        ss += __shfl_xor(ss, 32, 64);
        sd += __shfl_xor(sd, 16, 64);
        sd += __shfl_xor(sd, 32, 64);
        if (cr == 0) {
            float mean = s * (1.f / 512.f);
            float var = ss * (1.f / 512.f) - mean * mean;
            logits[((size_t)n * 8 + h) * 16 + m] =
                (sd - mean * sw) * rsqrtf(var + 1e-5f) + ba2v;
        }
    }
}

// ---------------------------------------------------------------------------
// Softmax over M per (n,h) + context aggregation -> scec bf16 [N,640]
// ---------------------------------------------------------------------------
__global__ __launch_bounds__(256) void smax_agg_kernel(const float* __restrict__ logits,
                                                       const us* __restrict__ qkv,
                                                       const us* __restrict__ edge,
                                                       const int* __restrict__ nbr,
                                                       us* __restrict__ scec) {
    __shared__ float attn[128];
    __shared__ int jn[16];
    int n = blockIdx.x, tid = threadIdx.x;
    if (tid < 16) jn[tid] = nbr[n * 16 + tid];
    if (tid < 128) {
        float lg = logits[(size_t)n * 128 + tid];
        float mx = lg;
#pragma unroll
        for (int o = 8; o; o >>= 1) mx = fmaxf(mx, __shfl_xor(mx, o, 16));
        float e = expf(lg - mx);
        float se = e;
#pragma unroll
        for (int o = 8; o; o >>= 1) se += __shfl_xor(se, o, 16);
        attn[tid] = e / se;
    }
    __syncthreads();
    for (int c = tid; c < 640; c += 256) {
        float acc = 0.f;
        if (c < 512) {
            int h = c >> 6, t = c & 63;
#pragma unroll
            for (int m = 0; m < 16; ++m) {
                us kv = qkv[(size_t)jn[m] * 1536 + 1024 + h * 64 + t];
                acc = fmaf(attn[h * 16 + m], b2f(kv), acc);
            }
        } else {
            int d = c - 512, h = d >> 4, t = d & 15;
#pragma unroll
            for (int m = 0; m < 16; ++m) {
                us ev = edge[((size_t)n * 16 + m) * 128 + h * 16 + t];
                acc = fmaf(attn[h * 16 + m], b2f(ev), acc);
            }
        }
        scec[(size_t)n * 640 + c] = f2bf(acc);
    }
}

// ---------------------------------------------------------------------------
extern "C" void kernel_launch(void* const* d_in, const int* in_sizes, int n_in,
                              void* d_out, int out_size, void* d_ws, size_t ws_size,
                              hipStream_t stream) {
    const float* gene_exp = (const float*)d_in[0];
    const float* token_embs = (const float*)d_in[1];
    const float* coords = (const float*)d_in[2];
    const int* nbr = (const int*)d_in[3];
    const float* w_qkv = (const float*)d_in[4];
    const float* b_qkv = (const float*)d_in[5];
    const float* wa1 = (const float*)d_in[6];
    const float* ba1 = (const float*)d_in[7];
    const float* wa2 = (const float*)d_in[8];
    const float* ba2 = (const float*)d_in[9];
    const float* we1 = (const float*)d_in[10];
    const float* be1 = (const float*)d_in[11];
    const float* we2 = (const float*)d_in[12];
    const float* be2 = (const float*)d_in[13];
    const float* wo1 = (const float*)d_in[14];
    const float* bo1 = (const float*)d_in[15];
    const float* wo2 = (const float*)d_in[16];
    const float* bo2 = (const float*)d_in[17];
    const float* wm1 = (const float*)d_in[18];
    const float* bm1 = (const float*)d_in[19];
    const float* wm2 = (const float*)d_in[20];
    const float* bm2 = (const float*)d_in[21];
    const float* wg1 = (const float*)d_in[22];
    const float* bg1 = (const float*)d_in[23];
    const float* wg2 = (const float*)d_in[24];
    const float* bg2 = (const float*)d_in[25];

    float* out = (float*)d_out;
    float* gene_out = out;             // [2048, 50]
    float* tok_out = out + 2048 * 50;  // [2048, 512]

    float* ws = (float*)d_ws;
    size_t o = 0;
    auto alloc = [&](size_t nf) {
        float* p = ws + o;
        o += nf;
        return p;
    };
    us* x_ln_bf = (us*)alloc((size_t)2048 * 512 / 2);
    us* qkv_bf = (us*)alloc((size_t)2048 * 1536 / 2);
    us* q2b = (us*)alloc((size_t)16384 * 64 / 2);
    us* k2b = (us*)alloc((size_t)16384 * 64 / 2);
    us* qpb = (us*)alloc((size_t)16384 * 512 / 2);
    us* kgb = (us*)alloc((size_t)16384 * 512 / 2);
    float* gep = alloc((size_t)2048 * 512);
    us* gepb = (us*)alloc((size_t)2048 * 512 / 2);
    us* edgeb = (us*)alloc(((size_t)2048 * 2048 + 32) / 2);
    float* logitsb = alloc((size_t)2048 * 128);
    us* scec_bf = (us*)alloc((size_t)2048 * 640 / 2);
    float* buf1 = alloc((size_t)2048 * 512);
    us* buf1_bf = (us*)alloc((size_t)2048 * 512 / 2);
    float* buf2 = alloc((size_t)2048 * 2048);
    us* buf2_bf = (us*)alloc((size_t)2048 * 2048 / 2);
    float* tok1 = alloc((size_t)2048 * 512);
    us* tok1_bf = (us*)alloc((size_t)2048 * 512 / 2);
    us* tokout_bf = (us*)alloc((size_t)2048 * 512 / 2);
    us* u_bf = (us*)alloc((size_t)32768 * 128 / 2);
    float* projs = alloc((size_t)32768 * 2);
    float* rns = alloc((size_t)32768);
    us* gene_bf = (us*)alloc((size_t)2048 * 64 / 2);
    us* qkvT = (us*)alloc((size_t)1536 * 512 / 2);
    us* wa1qT = (us*)alloc((size_t)512 * 64 / 2);
    us* wa1kT = (us*)alloc((size_t)512 * 64 / 2);
    us* wa1gT = (us*)alloc((size_t)512 * 64 / 2);
    us* we2T = (us*)alloc((size_t)128 * 128 / 2);
    us* wo1T = (us*)alloc((size_t)512 * 640 / 2);
    us* wo2T = (us*)alloc((size_t)512 * 512 / 2);
    us* wm1T = (us*)alloc((size_t)2048 * 512 / 2);
    us* wm2T = (us*)alloc((size_t)512 * 2048 / 2);
    us* wg1T = (us*)alloc((size_t)512 * 512 / 2);
    us* wg2T = (us*)alloc((size_t)128 * 512 / 2);
    us* wesT = (us*)alloc((size_t)512 * 32 / 2);
    if (o * sizeof(float) > ws_size) return;  // ~122 MB required

    auto G = [&](const us* A, const us* Bt, const float* bias, const float* resid,
                 const float* residH, float* outF, us* outB, int M, int K, int N,
                 int Nout) {
        gemm_bf16_kernel<<<dim3(N / 128, M / 128), 256, 0, stream>>>(
            A, Bt, bias, resid, residH, outF, outB, M, K, N, Nout);
    };

    // 0. weight transpose-casts (one launch) + wesT + gene cast
    hipMemsetAsync(wg2T, 0, (size_t)128 * 512 * 2, stream);  // pad rows 50..127
    {
        TC11 P;
        auto set = [&](int i, const float* s, us* d, int K, int N, int Kld, int& acc) {
            P.j[i] = {s, d, K, N, Kld, acc};
            acc += ((N + 31) / 32) * ((Kld + 31) / 32);
        };
        int acc = 0;
        set(0, w_qkv, qkvT, 512, 1536, 512, acc);
        set(1, wa1, wa1qT, 64, 512, 64, acc);
        set(2, wa1 + 64 * 512, wa1kT, 64, 512, 64, acc);
        set(3, we2, we2T, 128, 128, 128, acc);
        set(4, wo1, wo1T, 640, 512, 640, acc);
        set(5, wo2, wo2T, 512, 512, 512, acc);
        set(6, wm1, wm1T, 512, 2048, 512, acc);
        set(7, wm2, wm2T, 2048, 512, 2048, acc);
        set(8, wg1, wg1T, 512, 512, 512, acc);
        set(9, wa1 + 144 * 512, wa1gT, 50, 512, 64, acc);  // K-padded to 64
        set(10, wg2, wg2T, 512, 50, 512, acc);             // rows 50..127 = memset 0
        tcast_all<<<acc, 256, 0, stream>>>(P);
        wesT_kernel<<<64, 256, 0, stream>>>(wa1, wesT);
        gene_cast_kernel<<<512, 256, 0, stream>>>(gene_exp, gene_bf);
    }

    // 1. x_ln_bf = LN(token_embs) (bf16)
    act_ln_kernel<<<2048, 256, 0, stream>>>(nullptr, x_ln_bf, token_embs, 512, 0);
    // 2. qkv = x_ln @ w_qkv + b_qkv (bf16)
    G(x_ln_bf, qkvT, b_qkv, nullptr, nullptr, nullptr, qkv_bf, 2048, 512, 1536, 1536);
    // 3. repack q,k -> bf16 [16384,64]
    repack_qk<<<1024, 256, 0, stream>>>(qkv_bf, q2b, k2b);
    // 4. gene fc1 piece via MFMA (K padded to 64) -> gep fp32 + gepb bf16
    G(gene_bf, wa1gT, nullptr, nullptr, nullptr, gep, gepb, 2048, 64, 512, 512);
    // 5. qpb = q@wa1_q + ba1 (bf16); kg = k@wa1_k + gep[row>>3] (bf16)
    G(q2b, wa1qT, ba1, nullptr, nullptr, nullptr, qpb, 16384, 64, 512, 512);
    G(k2b, wa1kT, nullptr, nullptr, gep, nullptr, kgb, 16384, 64, 512, 512);
    // 6. frame-averaged edge features -> edgeb bf16 (incl. be2)
    proj_kernel<<<128, 256, 0, stream>>>(coords, nbr, projs, rns);
    frame_mlp1_kernel<<<8192, 256, 0, stream>>>(projs, rns, we1, be1, u_bf);
    G(u_bf, we2T, be2, nullptr, nullptr, nullptr, edgeb, 32768, 128, 128, 128);
    // 7. fused logits (transposed MFMA edge term + assemble + gelu + LN-dot)
    logits_fused_kernel<<<2048, 256, 0, stream>>>(qpb, kgb, gepb, edgeb, wesT, nbr, wa2,
                                                  ba2, logitsb);
    // 8. softmax + context aggregation -> scec bf16
    smax_agg_kernel<<<2048, 256, 0, stream>>>(logitsb, qkv_bf, edgeb, nbr, scec_bf);
    // 9. ctx = mlp2(scec, wo1, wo2); tok1 = token_embs + ctx
    G(scec_bf, wo1T, bo1, nullptr, nullptr, buf1, nullptr, 2048, 640, 512, 512);
    act_ln_kernel<<<2048, 256, 0, stream>>>(nullptr, buf1_bf, buf1, 512, 1);
    G(buf1_bf, wo2T, bo2, token_embs, nullptr, tok1, tok1_bf, 2048, 512, 512, 512);
    // 10. tok2 = tok1 + mlp2(tok1, wm1, wm2) -> d_out tok section
    G(tok1_bf, wm1T, bm1, nullptr, nullptr, buf2, nullptr, 2048, 512, 2048, 2048);
    act_ln_kernel<<<2048, 256, 0, stream>>>(nullptr, buf2_bf, buf2, 2048, 1);
    G(buf2_bf, wm2T, bm2, tok1, nullptr, tok_out, tokout_bf, 2048, 2048, 512, 512);
    // 11. gene_out = mlp2(tok2, wg1, wg2)
    G(tokout_bf, wg1T, bg1, nullptr, nullptr, buf1, nullptr, 2048, 512, 512, 512);
    act_ln_kernel<<<2048, 256, 0, stream>>>(nullptr, buf1_bf, buf1, 512, 1);
    G(buf1_bf, wg2T, bg2, nullptr, nullptr, gene_out, nullptr, 2048, 512, 128, 50);
}

// Round 10
// 418.990 us; speedup vs baseline: 1.1143x; 1.0100x over previous
//
#include <hip/hip_runtime.h>
#include <math.h>

// Problem constants
#define NN 2048
#define MM 16
#define DD 512
#define DE 128
#define HH 8
#define GG 50
#define DH 64
#define DEH 16

typedef __attribute__((ext_vector_type(8))) short bf8_t;   // 8 bf16 = 4 VGPRs
typedef __attribute__((ext_vector_type(4))) float f4_t;    // MFMA accumulator
typedef __attribute__((ext_vector_type(2))) float f2_t;    // packed f32 pair
typedef unsigned short us;

// Async global->LDS 16B copy. LDS dest must be wave-uniform base; HW writes
// base + lane*16. Global src is per-lane.
__device__ __forceinline__ void gload16(const us* g, us* l) {
    __builtin_amdgcn_global_load_lds(
        (const __attribute__((address_space(1))) unsigned int*)g,
        (__attribute__((address_space(3))) unsigned int*)l, 16, 0, 0);
}

// Branchless tanh-approx GELU (max |err| vs erf-gelu ~3e-3)
__device__ __forceinline__ float gelu_f(float x) {
    float u = 1.5957691216f * fmaf(0.044715f * x, x * x, x);
    u = fminf(fmaxf(u, -30.f), 30.f);
    float e = __expf(u);
    float t = fmaf(-2.f, __builtin_amdgcn_rcpf(e + 1.f), 1.f);  // tanh(u/2)
    float hx = 0.5f * x;
    return fmaf(hx, t, hx);
}

// Packed-pair gelu, clamp-free (exp overflow saturates to the right limits:
// e=inf -> rcp=0 -> t=1 -> g=x;  e=0 -> t=-1 -> g=0).
__device__ __forceinline__ f2_t gelu2(f2_t x) {
    f2_t u = ((x * 0.044715f) * (x * x) + x) * 1.5957691216f;
    f2_t e1;
    e1.x = __expf(u.x) + 1.f;
    e1.y = __expf(u.y) + 1.f;
    f2_t r;
    r.x = __builtin_amdgcn_rcpf(e1.x);
    r.y = __builtin_amdgcn_rcpf(e1.y);
    f2_t t = r * (-2.f) + 1.f;
    f2_t hx = x * 0.5f;
    return hx * t + hx;
}

__device__ __forceinline__ float wsum(float v) {
#pragma unroll
    for (int o = 32; o; o >>= 1) v += __shfl_xor(v, o, 64);
    return v;
}

__device__ __forceinline__ us f2bf(float x) {
    union { float f; unsigned int u; } v;
    v.f = x;
    unsigned int r = v.u + 0x7FFFu + ((v.u >> 16) & 1u);  // RNE
    return (us)(r >> 16);
}

__device__ __forceinline__ float bfu(unsigned int u) {
    union { unsigned int x; float f; } v;
    v.x = u;
    return v.f;
}
#define BF_LO(u) bfu((u) << 16)
#define BF_HI(u) bfu((u) & 0xFFFF0000u)
__device__ __forceinline__ float b2f(us u) { return bfu((unsigned int)u << 16); }

// ---------------------------------------------------------------------------
// Row-wise (optional GELU) + LayerNorm. Writes fp32 and/or bf16 output.
// ---------------------------------------------------------------------------
__global__ __launch_bounds__(256) void act_ln_kernel(float* __restrict__ outF,
                                                     us* __restrict__ outB,
                                                     const float* __restrict__ x,
                                                     int C, int do_gelu) {
    int row = blockIdx.x, tid = threadIdx.x;
    int nv = C >> 8;  // C is 512 or 2048
    float v[8];
    float s = 0.f, ss = 0.f;
    for (int i = 0; i < nv; ++i) {
        float val = x[(size_t)row * C + tid + (i << 8)];
        if (do_gelu) val = gelu_f(val);
        v[i] = val;
        s += val;
        ss += val * val;
    }
    __shared__ float red[4][2];
    s = wsum(s);
    ss = wsum(ss);
    int wid = tid >> 6, lane = tid & 63;
    if (lane == 0) { red[wid][0] = s; red[wid][1] = ss; }
    __syncthreads();
    s = red[0][0] + red[1][0] + red[2][0] + red[3][0];
    ss = red[0][1] + red[1][1] + red[2][1] + red[3][1];
    float mean = s / (float)C;
    float var = ss / (float)C - mean * mean;
    float rs = rsqrtf(var + 1e-5f);
    for (int i = 0; i < nv; ++i) {
        float y = (v[i] - mean) * rs;
        size_t idx = (size_t)row * C + tid + (i << 8);
        if (outF) outF[idx] = y;
        if (outB) outB[idx] = f2bf(y);
    }
}

// ---------------------------------------------------------------------------
// Fused transpose-casts: W [K,N] fp32 -> Wt [N,Kld] bf16 (zero-fill K..Kld),
// 11 jobs + wesT build + gene cast, all in one launch.
// ---------------------------------------------------------------------------
struct TCJob {
    const float* src;
    us* dst;
    int K, N, Kld, b0;
};
struct TC11 {
    TCJob j[11];
    int acc_end;
    const float* wa1_s;
    us* wesT_d;
    const float* gene_s;
    us* gene_d;
};

__global__ __launch_bounds__(256) void tcast_all(TC11 P) {
    __shared__ float tile[32][33];
    int b = blockIdx.x;
    if (b >= P.acc_end) {
        int lb = b - P.acc_end;
        if (lb < 64) {  // wesT: [512,32], t>=16 zero
            int idx = lb * 256 + threadIdx.x;
            int c = idx >> 5, t = idx & 31;
            P.wesT_d[idx] = (t < 16) ? f2bf(P.wa1_s[(size_t)(128 + t) * 512 + c]) : (us)0;
        } else {  // gene cast: [2048,64], c>=50 zero
            int idx = (lb - 64) * 256 + threadIdx.x;
            int r = idx >> 6, c = idx & 63;
            P.gene_d[idx] = (c < 50) ? f2bf(P.gene_s[r * 50 + c]) : (us)0;
        }
        return;
    }
    int ji = 0;
#pragma unroll
    for (int i = 1; i < 11; ++i)
        if (b >= P.j[i].b0) ji = i;
    const float* W = P.j[ji].src;
    us* Wt = P.j[ji].dst;
    int K = P.j[ji].K, N = P.j[ji].N, Kld = P.j[ji].Kld;
    int lb = b - P.j[ji].b0;
    int nbx = (N + 31) >> 5;
    int n0 = (lb % nbx) * 32, k0 = (lb / nbx) * 32;
    int tx = threadIdx.x & 31, ty = threadIdx.x >> 5;
#pragma unroll
    for (int p = 0; p < 4; ++p) {
        int k = k0 + ty + p * 8;
        tile[ty + p * 8][tx] = (k < K && n0 + tx < N) ? W[(size_t)k * N + n0 + tx] : 0.f;
    }
    __syncthreads();
#pragma unroll
    for (int p = 0; p < 4; ++p) {
        int n = n0 + ty + p * 8;
        if (n < N && k0 + tx < Kld) Wt[(size_t)n * Kld + k0 + tx] = f2bf(tile[tx][ty + p * 8]);
    }
}

// ---------------------------------------------------------------------------
// bf16 MFMA GEMM: out = A[M,K](bf16) @ Bt[N,K](bf16)^T (+bias[col])
//                 (+resid[M,Nout] fp32) (+residH[M/8,Nout] fp32, row-bcast 8)
// 128x128 tile, 4 waves (2x2). K-step 64. Double-buffered LDS with prefetch.
// If outB2 != null: 3-way column split (col>>9) into outB/outB2/outB3, each
// [M,512] (used to peel q/k/v from the qkv GEMM without a repack pass).
// Requires: 128|M, 128|N, 64|K. Output guarded/strided by Nout (<=N).
// ---------------------------------------------------------------------------
__global__ __launch_bounds__(256) void gemm_bf16_kernel(
    const us* __restrict__ A, const us* __restrict__ Bt,
    const float* __restrict__ bias, const float* __restrict__ resid,
    const float* __restrict__ residH,
    float* __restrict__ outF, us* __restrict__ outB,
    us* __restrict__ outB2, us* __restrict__ outB3,
    int M, int K, int N, int Nout) {
    __shared__ us As[2][128 * 64];
    __shared__ us Bs[2][128 * 64];
    int tid = threadIdx.x;
    int lane = tid & 63;
    int w = tid >> 6;
    int wr = w >> 1, wc = w & 1;
    int row0 = blockIdx.y * 128, col0 = blockIdx.x * 128;
    f4_t acc[4][4];
#pragma unroll
    for (int a = 0; a < 4; ++a)
#pragma unroll
        for (int b = 0; b < 4; ++b) {
            acc[a][b][0] = 0.f; acc[a][b][1] = 0.f;
            acc[a][b][2] = 0.f; acc[a][b][3] = 0.f;
        }

    auto stage = [&](int buf, int kt) {
#pragma unroll
        for (int p = 0; p < 4; ++p) {
            int id = p * 256 + tid;          // 1024 chunks of 16B
            int r = id >> 3, cch = id & 7;
            int kc = cch ^ (r & 7);          // swizzled source chunk
            int wb = p * 256 + (tid & 192);  // wave-uniform LDS chunk base
            gload16(A + (size_t)(row0 + r) * K + kt + kc * 8, As[buf] + wb * 8);
            gload16(Bt + (size_t)(col0 + r) * K + kt + kc * 8, Bs[buf] + wb * 8);
        }
    };

    int nkt = K >> 6;
    stage(0, 0);
    __syncthreads();  // drain prologue loads
    for (int t = 0; t < nkt; ++t) {
        int cur = t & 1;
        if (t + 1 < nkt) stage(cur ^ 1, (t + 1) << 6);  // prefetch next tile
#pragma unroll
        for (int kk = 0; kk < 2; ++kk) {
            bf8_t af[4], bfr[4];
            int kslot = kk * 4 + (lane >> 4);
#pragma unroll
            for (int mi = 0; mi < 4; ++mi) {
                int r = wr * 64 + mi * 16 + (lane & 15);
                af[mi] = *(const bf8_t*)((char*)As[cur] + r * 128 + ((kslot ^ (r & 7)) * 16));
            }
#pragma unroll
            for (int ni = 0; ni < 4; ++ni) {
                int r = wc * 64 + ni * 16 + (lane & 15);
                bfr[ni] = *(const bf8_t*)((char*)Bs[cur] + r * 128 + ((kslot ^ (r & 7)) * 16));
            }
#pragma unroll
            for (int mi = 0; mi < 4; ++mi)
#pragma unroll
                for (int ni = 0; ni < 4; ++ni)
                    acc[mi][ni] = __builtin_amdgcn_mfma_f32_16x16x32_bf16(
                        af[mi], bfr[ni], acc[mi][ni], 0, 0, 0);
        }
        __syncthreads();  // drains prefetch (vmcnt0) + protects buffer reuse
    }
    int cr = lane >> 4, cc = lane & 15;
#pragma unroll
    for (int mi = 0; mi < 4; ++mi)
#pragma unroll
        for (int ni = 0; ni < 4; ++ni) {
            int col = col0 + wc * 64 + ni * 16 + cc;
            if (col >= Nout) continue;
            float bv = bias ? bias[col] : 0.f;
#pragma unroll
            for (int j = 0; j < 4; ++j) {
                int row = row0 + wr * 64 + mi * 16 + cr * 4 + j;
                float v = acc[mi][ni][j] + bv;
                if (resid) v += resid[(size_t)row * Nout + col];
                if (residH) v += residH[(size_t)(row >> 3) * Nout + col];
                if (outF) outF[(size_t)row * Nout + col] = v;
                if (outB) {
                    if (outB2) {
                        int seg = col >> 9, cl = col & 511;
                        us* dst = seg == 0 ? outB : (seg == 1 ? outB2 : outB3);
                        dst[(size_t)row * 512 + cl] = f2bf(v);
                    } else {
                        outB[(size_t)row * Nout + col] = f2bf(v);
                    }
                }
            }
        }
}

// ---------------------------------------------------------------------------
// Frame projections: per (n,m) PCA-frame projection + radial norm.
// ---------------------------------------------------------------------------
__global__ __launch_bounds__(256) void proj_kernel(const float* __restrict__ coords,
                                                   const int* __restrict__ nbr,
                                                   float* __restrict__ projs,
                                                   float* __restrict__ rns) {
    int node = blockIdx.x * 16 + (threadIdx.x >> 4);
    int m = threadIdx.x & 15;
    float cx = coords[node * 2], cy = coords[node * 2 + 1];
    int j = nbr[node * 16 + m];
    float rx = coords[j * 2] - cx;
    float ry = coords[j * 2 + 1] - cy;
    float rn = sqrtf(rx * rx + ry * ry);
    float mx = rx, my = ry;
#pragma unroll
    for (int o = 8; o; o >>= 1) { mx += __shfl_xor(mx, o, 16); my += __shfl_xor(my, o, 16); }
    mx *= 0.0625f;
    my *= 0.0625f;
    float xcx = rx - mx, xcy = ry - my;
    float sxx = xcx * xcx, sxy = xcx * xcy, syy = xcy * xcy;
#pragma unroll
    for (int o = 8; o; o >>= 1) {
        sxx += __shfl_xor(sxx, o, 16);
        sxy += __shfl_xor(sxy, o, 16);
        syy += __shfl_xor(syy, o, 16);
    }
    double a = (double)sxx, b = (double)sxy, c = (double)syy;
    double diff = 0.5 * (a - c);
    double disc = sqrt(diff * diff + b * b);
    double l2 = 0.5 * (a + c) + disc;
    double v2x = b, v2y = l2 - a;
    double nn2 = sqrt(v2x * v2x + v2y * v2y);
    if (nn2 < 1e-30) { v2x = (a >= c) ? 1.0 : 0.0; v2y = 1.0 - v2x; nn2 = 1.0; }
    v2x /= nn2;
    v2y /= nn2;
    double v1x = -v2y, v1y = v2x;  // eigenvector of smaller eigenvalue
    int row = node * 16 + m;
    projs[row * 2] = (float)((double)xcx * v1x + (double)xcy * v1y);
    projs[row * 2 + 1] = (float)((double)xcx * v2x + (double)xcy * v2y);
    rns[row] = rn;
}

// ---------------------------------------------------------------------------
// Frame MLP stage 1 -> u bf16: u[row,c] = 0.25*sum_f LN(gelu([frame,rn]@we1+be1))
// ---------------------------------------------------------------------------
__global__ __launch_bounds__(256) void frame_mlp1_kernel(const float* __restrict__ projs,
                                                         const float* __restrict__ rns,
                                                         const float* __restrict__ we1,
                                                         const float* __restrict__ be1,
                                                         us* __restrict__ u) {
    int row = blockIdx.x * 4 + (threadIdx.x >> 6);
    int lane = threadIdx.x & 63;
    float px = projs[row * 2], py = projs[row * 2 + 1], rn = rns[row];
    int c0 = lane, c1 = lane + 64;
    float w10a = we1[c0], w11a = we1[128 + c0], w12a = we1[256 + c0], b1a = be1[c0];
    float w10b = we1[c1], w11b = we1[128 + c1], w12b = we1[256 + c1], b1b = be1[c1];
    float acc0 = 0.f, acc1 = 0.f;
    const float opsx[4] = {-1.f, -1.f, 1.f, 1.f};
    const float opsy[4] = {-1.f, 1.f, -1.f, 1.f};
#pragma unroll
    for (int f = 0; f < 4; ++f) {
        float fx = opsx[f] * px, fy = opsy[f] * py;
        float h0 = gelu_f(fmaf(fx, w10a, fmaf(fy, w11a, fmaf(rn, w12a, b1a))));
        float h1 = gelu_f(fmaf(fx, w10b, fmaf(fy, w11b, fmaf(rn, w12b, b1b))));
        float s = wsum(h0 + h1);
        float ss = wsum(fmaf(h0, h0, h1 * h1));
        float mean = s * (1.f / 128.f);
        float var = ss * (1.f / 128.f) - mean * mean;
        float rs = rsqrtf(var + 1e-5f);
        acc0 += (h0 - mean) * rs;
        acc1 += (h1 - mean) * rs;
    }
    u[(size_t)row * 128 + c0] = f2bf(0.25f * acc0);
    u[(size_t)row * 128 + c1] = f2bf(0.25f * acc1);
}

// ---------------------------------------------------------------------------
// Fused logits + softmax + context aggregation. Per node n (block):
//  1) transposed-MFMA edge term + assemble + gelu + LN-dot -> lgs[128] (LDS)
//  2) in-block softmax over m per h
//  3) aggregate sc (v2b gather) + ec (Es, already in LDS) -> scec bf16
// Inner math in f2_t pairs so the backend can emit v_pk_*_f32.
// ---------------------------------------------------------------------------
__global__ __launch_bounds__(256) void logits_fused_kernel(
    const us* __restrict__ qpb,    // qp+ba1 bf16 [16384,512]
    const us* __restrict__ kg,     // kp+gep bf16 [16384,512]
    const us* __restrict__ gepb,   // bf16 [2048,512]
    const us* __restrict__ edgeb,  // bf16 [2048][16][128] (+32 pad at end)
    const us* __restrict__ wesT,   // bf16 [512,32], k=16..31 zero
    const int* __restrict__ nbr,
    const float* __restrict__ wa2,
    const float* __restrict__ ba2,
    const us* __restrict__ v2b,    // v bf16 [2048,512] (h*64+t)
    us* __restrict__ scec) {
    __shared__ us Es[2048 + 32];  // 4.2 KB: edge rows (m*8+h) x 16, 32B stride
    __shared__ us qmg[8 * 520];   // 8.1 KB: (qp+ba1-gep[n]) bf16, padded rows
    __shared__ float wa2s[512];   // 2 KB
    __shared__ float lgs[128];
    __shared__ float attn[128];
    __shared__ float sinv[8];
    __shared__ int jns[16];
    int n = blockIdx.x, tid = threadIdx.x;
    int lane = tid & 63;
    // sw = sum(wa2), redundantly per wave (pre-sync)
    float swv = 0.f;
#pragma unroll
    for (int i = 0; i < 8; ++i) swv += wa2[lane + 64 * i];
    float sw = wsum(swv);
    float ba2v = ba2[0];
    // stage
    {
        const uint* s2 = (const uint*)(edgeb + (size_t)n * 2048);
        uint* d2 = (uint*)Es;
        for (int i = tid; i < 1040; i += 256) d2[i] = s2[i];
        const uint* s3 = (const uint*)(qpb + (size_t)n * 4096);
        const uint* s4 = (const uint*)(gepb + (size_t)n * 512);
        uint* d3 = (uint*)qmg;
        for (int i = tid; i < 2048; i += 256) {
            uint q = s3[i], g = s4[i & 255];
            float lo = BF_LO(q) - BF_LO(g), hi = BF_HI(q) - BF_HI(g);
            d3[(i >> 8) * 260 + (i & 255)] = ((uint)f2bf(hi) << 16) | (uint)f2bf(lo);
        }
        for (int i = tid; i < 512; i += 256) wa2s[i] = wa2[i];
        if (tid < 16) jns[tid] = nbr[n * 16 + tid];
    }
    __syncthreads();

    int cc = lane & 15, cr = lane >> 4;
    int w = tid >> 6;
#pragma unroll
    for (int mt = 0; mt < 2; ++mt) {
        int mh = w * 32 + mt * 16 + cc;
        int m = mh >> 3, h = mh & 7;
        int j8h = jns[m] * 8 + h;
        const us* kgrow = kg + (size_t)j8h * 512;
        const us* qrow = qmg + h * 520;
        // B-operand fragment: edge row mh, k-slot cr (cr>=2 over-reads next
        // row's data which multiplies the zero wesT k=16..31 -> benign)
        bf8_t bfr = *(const bf8_t*)((const char*)Es + mh * 32 + cr * 16);
        f2_t s2v = {0.f, 0.f}, ss2 = {0.f, 0.f}, sd2 = {0.f, 0.f};
#pragma unroll 4
        for (int ct = 0; ct < 32; ++ct) {
            int chb = ct * 16 + cr * 4;  // this lane's 4 channels
            bf8_t af = *(const bf8_t*)(wesT + (ct * 16 + cc) * 32 + cr * 8);
            f4_t z = {0.f, 0.f, 0.f, 0.f};
            f4_t ep = __builtin_amdgcn_mfma_f32_16x16x32_bf16(af, bfr, z, 0, 0, 0);
            uint2 kg4 = *(const uint2*)(kgrow + chb);
            uint2 qp4 = *(const uint2*)(qrow + chb);
            float4 w4 = *(const float4*)(wa2s + chb);
            f2_t ep01 = {ep[0], ep[1]}, ep23 = {ep[2], ep[3]};
            f2_t q01 = {BF_LO(qp4.x), BF_HI(qp4.x)};
            f2_t q23 = {BF_LO(qp4.y), BF_HI(qp4.y)};
            f2_t k01 = {BF_LO(kg4.x), BF_HI(kg4.x)};
            f2_t k23 = {BF_LO(kg4.y), BF_HI(kg4.y)};
            f2_t g01 = gelu2(ep01 + q01 + k01);
            f2_t g23 = gelu2(ep23 + q23 + k23);
            s2v += g01;
            s2v += g23;
            ss2 = g01 * g01 + ss2;
            ss2 = g23 * g23 + ss2;
            f2_t w01 = {w4.x, w4.y}, w23 = {w4.z, w4.w};
            sd2 = g01 * w01 + sd2;
            sd2 = g23 * w23 + sd2;
        }
        float s = s2v.x + s2v.y, ss = ss2.x + ss2.y, sd = sd2.x + sd2.y;
        // reduce across the 4 cr groups (lanes 16/32 apart), cc preserved
        s += __shfl_xor(s, 16, 64);
        s += __shfl_xor(s, 32, 64);
        ss += __shfl_xor(ss, 16, 64);
        ss += __shfl_xor(ss, 32, 64);
        sd += __shfl_xor(sd, 16, 64);
        sd += __shfl_xor(sd, 32, 64);
        if (cr == 0) {
            float mean = s * (1.f / 512.f);
            float var = ss * (1.f / 512.f) - mean * mean;
            lgs[mh] = (sd - mean * sw) * rsqrtf(var + 1e-5f) + ba2v;
        }
    }
    __syncthreads();
    // softmax over m (16 values, stride 8 in lgs) per h
    if (tid < 128) {
        int h = tid & 7;
        float mx = lgs[h];
#pragma unroll
        for (int mm = 1; mm < 16; ++mm) mx = fmaxf(mx, lgs[mm * 8 + h]);
        attn[tid] = __expf(lgs[tid] - mx);
    }
    __syncthreads();
    if (tid < 8) {
        float se = 0.f;
#pragma unroll
        for (int mm = 0; mm < 16; ++mm) se += attn[mm * 8 + tid];
        sinv[tid] = 1.f / se;
    }
    __syncthreads();
    // aggregation -> scec [n, 640] = [sc(512) | ec(128)]
    for (int c = tid; c < 640; c += 256) {
        float acc = 0.f;
        int h;
        if (c < 512) {
            h = c >> 6;
            int t = c & 63;
#pragma unroll
            for (int m = 0; m < 16; ++m)
                acc = fmaf(attn[m * 8 + h], b2f(v2b[(size_t)jns[m] * 512 + h * 64 + t]), acc);
        } else {
            int d = c - 512;
            h = d >> 4;
            int t = d & 15;
#pragma unroll
            for (int m = 0; m < 16; ++m)
                acc = fmaf(attn[m * 8 + h], b2f(Es[m * 128 + h * 16 + t]), acc);
        }
        scec[(size_t)n * 640 + c] = f2bf(acc * sinv[h]);
    }
}

// ---------------------------------------------------------------------------
extern "C" void kernel_launch(void* const* d_in, const int* in_sizes, int n_in,
                              void* d_out, int out_size, void* d_ws, size_t ws_size,
                              hipStream_t stream) {
    const float* gene_exp = (const float*)d_in[0];
    const float* token_embs = (const float*)d_in[1];
    const float* coords = (const float*)d_in[2];
    const int* nbr = (const int*)d_in[3];
    const float* w_qkv = (const float*)d_in[4];
    const float* b_qkv = (const float*)d_in[5];
    const float* wa1 = (const float*)d_in[6];
    const float* ba1 = (const float*)d_in[7];
    const float* wa2 = (const float*)d_in[8];
    const float* ba2 = (const float*)d_in[9];
    const float* we1 = (const float*)d_in[10];
    const float* be1 = (const float*)d_in[11];
    const float* we2 = (const float*)d_in[12];
    const float* be2 = (const float*)d_in[13];
    const float* wo1 = (const float*)d_in[14];
    const float* bo1 = (const float*)d_in[15];
    const float* wo2 = (const float*)d_in[16];
    const float* bo2 = (const float*)d_in[17];
    const float* wm1 = (const float*)d_in[18];
    const float* bm1 = (const float*)d_in[19];
    const float* wm2 = (const float*)d_in[20];
    const float* bm2 = (const float*)d_in[21];
    const float* wg1 = (const float*)d_in[22];
    const float* bg1 = (const float*)d_in[23];
    const float* wg2 = (const float*)d_in[24];
    const float* bg2 = (const float*)d_in[25];

    float* out = (float*)d_out;
    float* gene_out = out;             // [2048, 50]
    float* tok_out = out + 2048 * 50;  // [2048, 512]

    float* ws = (float*)d_ws;
    size_t o = 0;
    auto alloc = [&](size_t nf) {
        float* p = ws + o;
        o += nf;
        return p;
    };
    us* x_ln_bf = (us*)alloc((size_t)2048 * 512 / 2);
    us* q2b = (us*)alloc((size_t)16384 * 64 / 2);
    us* k2b = (us*)alloc((size_t)16384 * 64 / 2);
    us* v2b = (us*)alloc((size_t)2048 * 512 / 2);
    us* qpb = (us*)alloc((size_t)16384 * 512 / 2);
    us* kgb = (us*)alloc((size_t)16384 * 512 / 2);
    float* gep = alloc((size_t)2048 * 512);
    us* gepb = (us*)alloc((size_t)2048 * 512 / 2);
    us* edgeb = (us*)alloc(((size_t)2048 * 2048 + 32) / 2);
    us* scec_bf = (us*)alloc((size_t)2048 * 640 / 2);
    float* buf1 = alloc((size_t)2048 * 512);
    us* buf1_bf = (us*)alloc((size_t)2048 * 512 / 2);
    float* buf2 = alloc((size_t)2048 * 2048);
    us* buf2_bf = (us*)alloc((size_t)2048 * 2048 / 2);
    float* tok1 = alloc((size_t)2048 * 512);
    us* tok1_bf = (us*)alloc((size_t)2048 * 512 / 2);
    us* tokout_bf = (us*)alloc((size_t)2048 * 512 / 2);
    us* u_bf = (us*)alloc((size_t)32768 * 128 / 2);
    float* projs = alloc((size_t)32768 * 2);
    float* rns = alloc((size_t)32768);
    us* gene_bf = (us*)alloc((size_t)2048 * 64 / 2);
    us* qkvT = (us*)alloc((size_t)1536 * 512 / 2);
    us* wa1qT = (us*)alloc((size_t)512 * 64 / 2);
    us* wa1kT = (us*)alloc((size_t)512 * 64 / 2);
    us* wa1gT = (us*)alloc((size_t)512 * 64 / 2);
    us* we2T = (us*)alloc((size_t)128 * 128 / 2);
    us* wo1T = (us*)alloc((size_t)512 * 640 / 2);
    us* wo2T = (us*)alloc((size_t)512 * 512 / 2);
    us* wm1T = (us*)alloc((size_t)2048 * 512 / 2);
    us* wm2T = (us*)alloc((size_t)512 * 2048 / 2);
    us* wg1T = (us*)alloc((size_t)512 * 512 / 2);
    us* wg2T = (us*)alloc((size_t)128 * 512 / 2);
    us* wesT = (us*)alloc((size_t)512 * 32 / 2);
    if (o * sizeof(float) > ws_size) return;  // ~120 MB required

    auto G = [&](const us* A, const us* Bt, const float* bias, const float* resid,
                 const float* residH, float* outF, us* outB, us* outB2, us* outB3,
                 int M, int K, int N, int Nout) {
        gemm_bf16_kernel<<<dim3(N / 128, M / 128), 256, 0, stream>>>(
            A, Bt, bias, resid, residH, outF, outB, outB2, outB3, M, K, N, Nout);
    };

    // 0. weight transpose-casts + wesT + gene cast (one launch)
    hipMemsetAsync(wg2T, 0, (size_t)128 * 512 * 2, stream);  // pad rows 50..127
    {
        TC11 P;
        auto set = [&](int i, const float* s, us* d, int K, int N, int Kld, int& acc) {
            P.j[i] = {s, d, K, N, Kld, acc};
            acc += ((N + 31) / 32) * ((Kld + 31) / 32);
        };
        int acc = 0;
        set(0, w_qkv, qkvT, 512, 1536, 512, acc);
        set(1, wa1, wa1qT, 64, 512, 64, acc);
        set(2, wa1 + 64 * 512, wa1kT, 64, 512, 64, acc);
        set(3, we2, we2T, 128, 128, 128, acc);
        set(4, wo1, wo1T, 640, 512, 640, acc);
        set(5, wo2, wo2T, 512, 512, 512, acc);
        set(6, wm1, wm1T, 512, 2048, 512, acc);
        set(7, wm2, wm2T, 2048, 512, 2048, acc);
        set(8, wg1, wg1T, 512, 512, 512, acc);
        set(9, wa1 + 144 * 512, wa1gT, 50, 512, 64, acc);  // K-padded to 64
        set(10, wg2, wg2T, 512, 50, 512, acc);             // rows 50..127 = memset 0
        P.acc_end = acc;
        P.wa1_s = wa1;
        P.wesT_d = wesT;
        P.gene_s = gene_exp;
        P.gene_d = gene_bf;
        tcast_all<<<acc + 64 + 512, 256, 0, stream>>>(P);
    }

    // 1. x_ln_bf = LN(token_embs) (bf16)
    act_ln_kernel<<<2048, 256, 0, stream>>>(nullptr, x_ln_bf, token_embs, 512, 0);
    // 2. qkv = x_ln @ w_qkv + b_qkv, epilogue-split into q2b | k2b | v2b
    G(x_ln_bf, qkvT, b_qkv, nullptr, nullptr, nullptr, q2b, k2b, v2b,
      2048, 512, 1536, 1536);
    // 3. gene fc1 piece via MFMA (K padded to 64) -> gep fp32 + gepb bf16
    G(gene_bf, wa1gT, nullptr, nullptr, nullptr, gep, gepb, nullptr, nullptr,
      2048, 64, 512, 512);
    // 4. qpb = q@wa1_q + ba1 (bf16); kg = k@wa1_k + gep[row>>3] (bf16)
    G(q2b, wa1qT, ba1, nullptr, nullptr, nullptr, qpb, nullptr, nullptr,
      16384, 64, 512, 512);
    G(k2b, wa1kT, nullptr, nullptr, gep, nullptr, kgb, nullptr, nullptr,
      16384, 64, 512, 512);
    // 5. frame-averaged edge features -> edgeb bf16 (incl. be2)
    proj_kernel<<<128, 256, 0, stream>>>(coords, nbr, projs, rns);
    frame_mlp1_kernel<<<8192, 256, 0, stream>>>(projs, rns, we1, be1, u_bf);
    G(u_bf, we2T, be2, nullptr, nullptr, nullptr, edgeb, nullptr, nullptr,
      32768, 128, 128, 128);
    // 6. fused logits + softmax + aggregation -> scec bf16
    logits_fused_kernel<<<2048, 256, 0, stream>>>(qpb, kgb, gepb, edgeb, wesT, nbr,
                                                  wa2, ba2, v2b, scec_bf);
    // 7. ctx = mlp2(scec, wo1, wo2); tok1 = token_embs + ctx
    G(scec_bf, wo1T, bo1, nullptr, nullptr, buf1, nullptr, nullptr, nullptr,
      2048, 640, 512, 512);
    act_ln_kernel<<<2048, 256, 0, stream>>>(nullptr, buf1_bf, buf1, 512, 1);
    G(buf1_bf, wo2T, bo2, token_embs, nullptr, tok1, tok1_bf, nullptr, nullptr,
      2048, 512, 512, 512);
    // 8. tok2 = tok1 + mlp2(tok1, wm1, wm2) -> d_out tok section
    G(tok1_bf, wm1T, bm1, nullptr, nullptr, buf2, nullptr, nullptr, nullptr,
      2048, 512, 2048, 2048);
    act_ln_kernel<<<2048, 256, 0, stream>>>(nullptr, buf2_bf, buf2, 2048, 1);
    G(buf2_bf, wm2T, bm2, tok1, nullptr, tok_out, tokout_bf, nullptr, nullptr,
      2048, 2048, 512, 512);
    // 9. gene_out = mlp2(tok2, wg1, wg2)
    G(tokout_bf, wg1T, bg1, nullptr, nullptr, buf1, nullptr, nullptr, nullptr,
      2048, 512, 512, 512);
    act_ln_kernel<<<2048, 256, 0, stream>>>(nullptr, buf1_bf, buf1, 512, 1);
    G(buf1_bf, wg2T, bg2, nullptr, nullptr, gene_out, nullptr, nullptr, nullptr,
      2048, 512, 128, 50);
}

// Round 11
// 352.946 us; speedup vs baseline: 1.3228x; 1.1871x over previous
//
#include <hip/hip_runtime.h>
#include <math.h>

// Problem constants
#define NN 2048
#define MM 16
#define DD 512
#define DE 128
#define HH 8
#define GG 50
#define DH 64
#define DEH 16

typedef __attribute__((ext_vector_type(8))) short bf8_t;   // 8 bf16 = 4 VGPRs
typedef __attribute__((ext_vector_type(4))) float f4_t;    // MFMA accumulator
typedef __attribute__((ext_vector_type(2))) float f2_t;    // packed f32 pair
typedef unsigned short us;

// Async global->LDS 16B copy. LDS dest must be wave-uniform base; HW writes
// base + lane*16. Global src is per-lane.
__device__ __forceinline__ void gload16(const us* g, us* l) {
    __builtin_amdgcn_global_load_lds(
        (const __attribute__((address_space(1))) unsigned int*)g,
        (__attribute__((address_space(3))) unsigned int*)l, 16, 0, 0);
}

// Branchless tanh-approx GELU (max |err| vs erf-gelu ~3e-3)
__device__ __forceinline__ float gelu_f(float x) {
    float u = 1.5957691216f * fmaf(0.044715f * x, x * x, x);
    u = fminf(fmaxf(u, -30.f), 30.f);
    float e = __expf(u);
    float t = fmaf(-2.f, __builtin_amdgcn_rcpf(e + 1.f), 1.f);  // tanh(u/2)
    float hx = 0.5f * x;
    return fmaf(hx, t, hx);
}

// Packed-pair gelu, clamp-free (exp overflow saturates to the right limits).
__device__ __forceinline__ f2_t gelu2(f2_t x) {
    f2_t u = ((x * 0.044715f) * (x * x) + x) * 1.5957691216f;
    f2_t e1;
    e1.x = __expf(u.x) + 1.f;
    e1.y = __expf(u.y) + 1.f;
    f2_t r;
    r.x = __builtin_amdgcn_rcpf(e1.x);
    r.y = __builtin_amdgcn_rcpf(e1.y);
    f2_t t = r * (-2.f) + 1.f;
    f2_t hx = x * 0.5f;
    return hx * t + hx;
}

__device__ __forceinline__ float wsum(float v) {
#pragma unroll
    for (int o = 32; o; o >>= 1) v += __shfl_xor(v, o, 64);
    return v;
}

__device__ __forceinline__ us f2bf(float x) {
    union { float f; unsigned int u; } v;
    v.f = x;
    unsigned int r = v.u + 0x7FFFu + ((v.u >> 16) & 1u);  // RNE
    return (us)(r >> 16);
}

__device__ __forceinline__ float bfu(unsigned int u) {
    union { unsigned int x; float f; } v;
    v.x = u;
    return v.f;
}
#define BF_LO(u) bfu((u) << 16)
#define BF_HI(u) bfu((u) & 0xFFFF0000u)
__device__ __forceinline__ float b2f(us u) { return bfu((unsigned int)u << 16); }

// ---------------------------------------------------------------------------
// Row-wise (optional GELU) + LayerNorm. Writes fp32 and/or bf16 output.
// ---------------------------------------------------------------------------
__global__ __launch_bounds__(256) void act_ln_kernel(float* __restrict__ outF,
                                                     us* __restrict__ outB,
                                                     const float* __restrict__ x,
                                                     int C, int do_gelu) {
    int row = blockIdx.x, tid = threadIdx.x;
    int nv = C >> 8;  // C is 512 or 2048
    float v[8];
    float s = 0.f, ss = 0.f;
    for (int i = 0; i < nv; ++i) {
        float val = x[(size_t)row * C + tid + (i << 8)];
        if (do_gelu) val = gelu_f(val);
        v[i] = val;
        s += val;
        ss += val * val;
    }
    __shared__ float red[4][2];
    s = wsum(s);
    ss = wsum(ss);
    int wid = tid >> 6, lane = tid & 63;
    if (lane == 0) { red[wid][0] = s; red[wid][1] = ss; }
    __syncthreads();
    s = red[0][0] + red[1][0] + red[2][0] + red[3][0];
    ss = red[0][1] + red[1][1] + red[2][1] + red[3][1];
    float mean = s / (float)C;
    float var = ss / (float)C - mean * mean;
    float rs = rsqrtf(var + 1e-5f);
    for (int i = 0; i < nv; ++i) {
        float y = (v[i] - mean) * rs;
        size_t idx = (size_t)row * C + tid + (i << 8);
        if (outF) outF[idx] = y;
        if (outB) outB[idx] = f2bf(y);
    }
}

// ---------------------------------------------------------------------------
// Fused LN(token_embs)->bf16 (blocks 0..2047) + frame projections (blocks
// 2048..2175; 16 nodes per block).
// ---------------------------------------------------------------------------
__global__ __launch_bounds__(256) void lnproj_kernel(const float* __restrict__ te,
                                                     us* __restrict__ x_ln_bf,
                                                     const float* __restrict__ coords,
                                                     const int* __restrict__ nbr,
                                                     float* __restrict__ projs,
                                                     float* __restrict__ rns) {
    int tid = threadIdx.x;
    if (blockIdx.x < 2048) {
        int row = blockIdx.x;
        float v0 = te[(size_t)row * 512 + tid];
        float v1 = te[(size_t)row * 512 + 256 + tid];
        __shared__ float red[4][2];
        float s = wsum(v0 + v1);
        float ss = wsum(fmaf(v0, v0, v1 * v1));
        int wid = tid >> 6, lane = tid & 63;
        if (lane == 0) { red[wid][0] = s; red[wid][1] = ss; }
        __syncthreads();
        s = red[0][0] + red[1][0] + red[2][0] + red[3][0];
        ss = red[0][1] + red[1][1] + red[2][1] + red[3][1];
        float mean = s * (1.f / 512.f);
        float var = ss * (1.f / 512.f) - mean * mean;
        float rs = rsqrtf(var + 1e-5f);
        x_ln_bf[(size_t)row * 512 + tid] = f2bf((v0 - mean) * rs);
        x_ln_bf[(size_t)row * 512 + 256 + tid] = f2bf((v1 - mean) * rs);
        return;
    }
    int node = (blockIdx.x - 2048) * 16 + (tid >> 4);
    int m = tid & 15;
    float cx = coords[node * 2], cy = coords[node * 2 + 1];
    int j = nbr[node * 16 + m];
    float rx = coords[j * 2] - cx;
    float ry = coords[j * 2 + 1] - cy;
    float rn = sqrtf(rx * rx + ry * ry);
    float mx = rx, my = ry;
#pragma unroll
    for (int o = 8; o; o >>= 1) { mx += __shfl_xor(mx, o, 16); my += __shfl_xor(my, o, 16); }
    mx *= 0.0625f;
    my *= 0.0625f;
    float xcx = rx - mx, xcy = ry - my;
    float sxx = xcx * xcx, sxy = xcx * xcy, syy = xcy * xcy;
#pragma unroll
    for (int o = 8; o; o >>= 1) {
        sxx += __shfl_xor(sxx, o, 16);
        sxy += __shfl_xor(sxy, o, 16);
        syy += __shfl_xor(syy, o, 16);
    }
    double a = (double)sxx, b = (double)sxy, c = (double)syy;
    double diff = 0.5 * (a - c);
    double disc = sqrt(diff * diff + b * b);
    double l2 = 0.5 * (a + c) + disc;
    double v2x = b, v2y = l2 - a;
    double nn2 = sqrt(v2x * v2x + v2y * v2y);
    if (nn2 < 1e-30) { v2x = (a >= c) ? 1.0 : 0.0; v2y = 1.0 - v2x; nn2 = 1.0; }
    v2x /= nn2;
    v2y /= nn2;
    double v1x = -v2y, v1y = v2x;  // eigenvector of smaller eigenvalue
    int row = node * 16 + m;
    projs[row * 2] = (float)((double)xcx * v1x + (double)xcy * v1y);
    projs[row * 2 + 1] = (float)((double)xcx * v2x + (double)xcy * v2y);
    rns[row] = rn;
}

// ---------------------------------------------------------------------------
// Fused transpose-casts: W [K,N] fp32 -> Wt [N,Kld] bf16 (zero-fill K..Kld),
// 11 jobs + wesT build + gene cast, all in one launch.
// ---------------------------------------------------------------------------
struct TCJob {
    const float* src;
    us* dst;
    int K, N, Kld, b0;
};
struct TC11 {
    TCJob j[11];
    int acc_end;
    const float* wa1_s;
    us* wesT_d;
    const float* gene_s;
    us* gene_d;
};

__global__ __launch_bounds__(256) void tcast_all(TC11 P) {
    __shared__ float tile[32][33];
    int b = blockIdx.x;
    if (b >= P.acc_end) {
        int lb = b - P.acc_end;
        if (lb < 64) {  // wesT: [512,32], t>=16 zero
            int idx = lb * 256 + threadIdx.x;
            int c = idx >> 5, t = idx & 31;
            P.wesT_d[idx] = (t < 16) ? f2bf(P.wa1_s[(size_t)(128 + t) * 512 + c]) : (us)0;
        } else {  // gene cast: [2048,64], c>=50 zero
            int idx = (lb - 64) * 256 + threadIdx.x;
            int r = idx >> 6, c = idx & 63;
            P.gene_d[idx] = (c < 50) ? f2bf(P.gene_s[r * 50 + c]) : (us)0;
        }
        return;
    }
    int ji = 0;
#pragma unroll
    for (int i = 1; i < 11; ++i)
        if (b >= P.j[i].b0) ji = i;
    const float* W = P.j[ji].src;
    us* Wt = P.j[ji].dst;
    int K = P.j[ji].K, N = P.j[ji].N, Kld = P.j[ji].Kld;
    int lb = b - P.j[ji].b0;
    int nbx = (N + 31) >> 5;
    int n0 = (lb % nbx) * 32, k0 = (lb / nbx) * 32;
    int tx = threadIdx.x & 31, ty = threadIdx.x >> 5;
#pragma unroll
    for (int p = 0; p < 4; ++p) {
        int k = k0 + ty + p * 8;
        tile[ty + p * 8][tx] = (k < K && n0 + tx < N) ? W[(size_t)k * N + n0 + tx] : 0.f;
    }
    __syncthreads();
#pragma unroll
    for (int p = 0; p < 4; ++p) {
        int n = n0 + ty + p * 8;
        if (n < N && k0 + tx < Kld) Wt[(size_t)n * Kld + k0 + tx] = f2bf(tile[tx][ty + p * 8]);
    }
}

// ---------------------------------------------------------------------------
// Batched bf16 MFMA GEMM (job table, up to 4 independent jobs per launch):
// out = A[M,Kstride](bf16) @ Bt[N,Kstride](bf16)^T over nkt K-steps of 64
// (+bias[col]) (+resid[M,Nout]) (+residH[M/8,Nout] row-bcast 8).
// 128x128 tile, 4 waves. Double-buffered LDS + prefetch.
// outB2!=null: 3-way col split (col>>9) into outB/outB2/outB3 (qkv peel).
// Split-K: pass pointers pre-offset, nkt = sub-K/64, outF = partial buffer.
// Requires: 128|M, 128|N, 64|Ksub.
// ---------------------------------------------------------------------------
struct GJob {
    const us* A;
    const us* Bt;
    const float* bias;
    const float* resid;
    const float* residH;
    float* outF;
    us* outB;
    us* outB2;
    us* outB3;
    int M, Kstride, nkt, N, Nout, b0;
};
struct GJobs {
    GJob j[4];
    int nj;
};

__global__ __launch_bounds__(256) void gemm_bf16_kernel(GJobs P) {
    __shared__ us As[2][128 * 64];
    __shared__ us Bs[2][128 * 64];
    int b = blockIdx.x;
    int ji = 0;
#pragma unroll
    for (int i = 1; i < 4; ++i)
        if (i < P.nj && b >= P.j[i].b0) ji = i;
    const us* A = P.j[ji].A;
    const us* Bt = P.j[ji].Bt;
    int Kst = P.j[ji].Kstride, nkt = P.j[ji].nkt;
    int Nn = P.j[ji].N, Nout = P.j[ji].Nout;
    int lb = b - P.j[ji].b0;
    int ncol = Nn >> 7;
    int col0 = (lb % ncol) << 7, row0 = (lb / ncol) << 7;

    int tid = threadIdx.x;
    int lane = tid & 63;
    int w = tid >> 6;
    int wr = w >> 1, wc = w & 1;
    f4_t acc[4][4];
#pragma unroll
    for (int a = 0; a < 4; ++a)
#pragma unroll
        for (int bb = 0; bb < 4; ++bb) {
            acc[a][bb][0] = 0.f; acc[a][bb][1] = 0.f;
            acc[a][bb][2] = 0.f; acc[a][bb][3] = 0.f;
        }

    auto stage = [&](int buf, int kt) {
#pragma unroll
        for (int p = 0; p < 4; ++p) {
            int id = p * 256 + tid;          // 1024 chunks of 16B
            int r = id >> 3, cch = id & 7;
            int kc = cch ^ (r & 7);          // swizzled source chunk
            int wb = p * 256 + (tid & 192);  // wave-uniform LDS chunk base
            gload16(A + (size_t)(row0 + r) * Kst + kt + kc * 8, As[buf] + wb * 8);
            gload16(Bt + (size_t)(col0 + r) * Kst + kt + kc * 8, Bs[buf] + wb * 8);
        }
    };

    stage(0, 0);
    __syncthreads();  // drain prologue loads
    for (int t = 0; t < nkt; ++t) {
        int cur = t & 1;
        if (t + 1 < nkt) stage(cur ^ 1, (t + 1) << 6);  // prefetch next tile
#pragma unroll
        for (int kk = 0; kk < 2; ++kk) {
            bf8_t af[4], bfr[4];
            int kslot = kk * 4 + (lane >> 4);
#pragma unroll
            for (int mi = 0; mi < 4; ++mi) {
                int r = wr * 64 + mi * 16 + (lane & 15);
                af[mi] = *(const bf8_t*)((char*)As[cur] + r * 128 + ((kslot ^ (r & 7)) * 16));
            }
#pragma unroll
            for (int ni = 0; ni < 4; ++ni) {
                int r = wc * 64 + ni * 16 + (lane & 15);
                bfr[ni] = *(const bf8_t*)((char*)Bs[cur] + r * 128 + ((kslot ^ (r & 7)) * 16));
            }
#pragma unroll
            for (int mi = 0; mi < 4; ++mi)
#pragma unroll
                for (int ni = 0; ni < 4; ++ni)
                    acc[mi][ni] = __builtin_amdgcn_mfma_f32_16x16x32_bf16(
                        af[mi], bfr[ni], acc[mi][ni], 0, 0, 0);
        }
        __syncthreads();  // drains prefetch (vmcnt0) + protects buffer reuse
    }
    const float* bias = P.j[ji].bias;
    const float* resid = P.j[ji].resid;
    const float* residH = P.j[ji].residH;
    float* outF = P.j[ji].outF;
    us* outB = P.j[ji].outB;
    us* outB2 = P.j[ji].outB2;
    us* outB3 = P.j[ji].outB3;
    int cr = lane >> 4, cc = lane & 15;
#pragma unroll
    for (int mi = 0; mi < 4; ++mi)
#pragma unroll
        for (int ni = 0; ni < 4; ++ni) {
            int col = col0 + wc * 64 + ni * 16 + cc;
            if (col >= Nout) continue;
            float bv = bias ? bias[col] : 0.f;
#pragma unroll
            for (int j = 0; j < 4; ++j) {
                int row = row0 + wr * 64 + mi * 16 + cr * 4 + j;
                float v = acc[mi][ni][j] + bv;
                if (resid) v += resid[(size_t)row * Nout + col];
                if (residH) v += residH[(size_t)(row >> 3) * Nout + col];
                if (outF) outF[(size_t)row * Nout + col] = v;
                if (outB) {
                    if (outB2) {
                        int seg = col >> 9, cl = col & 511;
                        us* dst = seg == 0 ? outB : (seg == 1 ? outB2 : outB3);
                        dst[(size_t)row * 512 + cl] = f2bf(v);
                    } else {
                        outB[(size_t)row * Nout + col] = f2bf(v);
                    }
                }
            }
        }
}

// ---------------------------------------------------------------------------
// Split-K combine for wm2: tok_out = sum4(partial) + bias + resid, + bf16.
// 1048576 elements, 4096 blocks x 256.
// ---------------------------------------------------------------------------
__global__ __launch_bounds__(256) void wm2_combine(const float* __restrict__ pk,
                                                   const float* __restrict__ bias,
                                                   const float* __restrict__ resid,
                                                   float* __restrict__ outF,
                                                   us* __restrict__ outB) {
    int idx = blockIdx.x * 256 + threadIdx.x;
    float v = pk[idx] + pk[idx + 1048576] + pk[idx + 2097152] + pk[idx + 3145728] +
              bias[idx & 511] + resid[idx];
    outF[idx] = v;
    outB[idx] = f2bf(v);
}

// ---------------------------------------------------------------------------
// Frame MLP stage 1 -> u bf16: u[row,c] = 0.25*sum_f LN(gelu([frame,rn]@we1+be1))
// ---------------------------------------------------------------------------
__global__ __launch_bounds__(256) void frame_mlp1_kernel(const float* __restrict__ projs,
                                                         const float* __restrict__ rns,
                                                         const float* __restrict__ we1,
                                                         const float* __restrict__ be1,
                                                         us* __restrict__ u) {
    int row = blockIdx.x * 4 + (threadIdx.x >> 6);
    int lane = threadIdx.x & 63;
    float px = projs[row * 2], py = projs[row * 2 + 1], rn = rns[row];
    int c0 = lane, c1 = lane + 64;
    float w10a = we1[c0], w11a = we1[128 + c0], w12a = we1[256 + c0], b1a = be1[c0];
    float w10b = we1[c1], w11b = we1[128 + c1], w12b = we1[256 + c1], b1b = be1[c1];
    float acc0 = 0.f, acc1 = 0.f;
    const float opsx[4] = {-1.f, -1.f, 1.f, 1.f};
    const float opsy[4] = {-1.f, 1.f, -1.f, 1.f};
#pragma unroll
    for (int f = 0; f < 4; ++f) {
        float fx = opsx[f] * px, fy = opsy[f] * py;
        float h0 = gelu_f(fmaf(fx, w10a, fmaf(fy, w11a, fmaf(rn, w12a, b1a))));
        float h1 = gelu_f(fmaf(fx, w10b, fmaf(fy, w11b, fmaf(rn, w12b, b1b))));
        float s = wsum(h0 + h1);
        float ss = wsum(fmaf(h0, h0, h1 * h1));
        float mean = s * (1.f / 128.f);
        float var = ss * (1.f / 128.f) - mean * mean;
        float rs = rsqrtf(var + 1e-5f);
        acc0 += (h0 - mean) * rs;
        acc1 += (h1 - mean) * rs;
    }
    u[(size_t)row * 128 + c0] = f2bf(0.25f * acc0);
    u[(size_t)row * 128 + c1] = f2bf(0.25f * acc1);
}

// ---------------------------------------------------------------------------
// Fused logits + softmax + context aggregation (see R9/R10).
// ---------------------------------------------------------------------------
__global__ __launch_bounds__(256) void logits_fused_kernel(
    const us* __restrict__ qpb,    // qp+ba1 bf16 [16384,512]
    const us* __restrict__ kg,     // kp+gep bf16 [16384,512]
    const us* __restrict__ gepb,   // bf16 [2048,512]
    const us* __restrict__ edgeb,  // bf16 [2048][16][128] (+32 pad at end)
    const us* __restrict__ wesT,   // bf16 [512,32], k=16..31 zero
    const int* __restrict__ nbr,
    const float* __restrict__ wa2,
    const float* __restrict__ ba2,
    const us* __restrict__ v2b,    // v bf16 [2048,512] (h*64+t)
    us* __restrict__ scec) {
    __shared__ us Es[2048 + 32];  // 4.2 KB: edge rows (m*8+h) x 16, 32B stride
    __shared__ us qmg[8 * 520];   // 8.1 KB: (qp+ba1-gep[n]) bf16, padded rows
    __shared__ float wa2s[512];   // 2 KB
    __shared__ float lgs[128];
    __shared__ float attn[128];
    __shared__ float sinv[8];
    __shared__ int jns[16];
    int n = blockIdx.x, tid = threadIdx.x;
    int lane = tid & 63;
    float swv = 0.f;
#pragma unroll
    for (int i = 0; i < 8; ++i) swv += wa2[lane + 64 * i];
    float sw = wsum(swv);
    float ba2v = ba2[0];
    {
        const uint* s2 = (const uint*)(edgeb + (size_t)n * 2048);
        uint* d2 = (uint*)Es;
        for (int i = tid; i < 1040; i += 256) d2[i] = s2[i];
        const uint* s3 = (const uint*)(qpb + (size_t)n * 4096);
        const uint* s4 = (const uint*)(gepb + (size_t)n * 512);
        uint* d3 = (uint*)qmg;
        for (int i = tid; i < 2048; i += 256) {
            uint q = s3[i], g = s4[i & 255];
            float lo = BF_LO(q) - BF_LO(g), hi = BF_HI(q) - BF_HI(g);
            d3[(i >> 8) * 260 + (i & 255)] = ((uint)f2bf(hi) << 16) | (uint)f2bf(lo);
        }
        for (int i = tid; i < 512; i += 256) wa2s[i] = wa2[i];
        if (tid < 16) jns[tid] = nbr[n * 16 + tid];
    }
    __syncthreads();

    int cc = lane & 15, cr = lane >> 4;
    int w = tid >> 6;
#pragma unroll
    for (int mt = 0; mt < 2; ++mt) {
        int mh = w * 32 + mt * 16 + cc;
        int m = mh >> 3, h = mh & 7;
        int j8h = jns[m] * 8 + h;
        const us* kgrow = kg + (size_t)j8h * 512;
        const us* qrow = qmg + h * 520;
        bf8_t bfr = *(const bf8_t*)((const char*)Es + mh * 32 + cr * 16);
        f2_t s2v = {0.f, 0.f}, ss2 = {0.f, 0.f}, sd2 = {0.f, 0.f};
#pragma unroll 4
        for (int ct = 0; ct < 32; ++ct) {
            int chb = ct * 16 + cr * 4;  // this lane's 4 channels
            bf8_t af = *(const bf8_t*)(wesT + (ct * 16 + cc) * 32 + cr * 8);
            f4_t z = {0.f, 0.f, 0.f, 0.f};
            f4_t ep = __builtin_amdgcn_mfma_f32_16x16x32_bf16(af, bfr, z, 0, 0, 0);
            uint2 kg4 = *(const uint2*)(kgrow + chb);
            uint2 qp4 = *(const uint2*)(qrow + chb);
            float4 w4 = *(const float4*)(wa2s + chb);
            f2_t ep01 = {ep[0], ep[1]}, ep23 = {ep[2], ep[3]};
            f2_t q01 = {BF_LO(qp4.x), BF_HI(qp4.x)};
            f2_t q23 = {BF_LO(qp4.y), BF_HI(qp4.y)};
            f2_t k01 = {BF_LO(kg4.x), BF_HI(kg4.x)};
            f2_t k23 = {BF_LO(kg4.y), BF_HI(kg4.y)};
            f2_t g01 = gelu2(ep01 + q01 + k01);
            f2_t g23 = gelu2(ep23 + q23 + k23);
            s2v += g01;
            s2v += g23;
            ss2 = g01 * g01 + ss2;
            ss2 = g23 * g23 + ss2;
            f2_t w01 = {w4.x, w4.y}, w23 = {w4.z, w4.w};
            sd2 = g01 * w01 + sd2;
            sd2 = g23 * w23 + sd2;
        }
        float s = s2v.x + s2v.y, ss = ss2.x + ss2.y, sd = sd2.x + sd2.y;
        s += __shfl_xor(s, 16, 64);
        s += __shfl_xor(s, 32, 64);
        ss += __shfl_xor(ss, 16, 64);
        ss += __shfl_xor(ss, 32, 64);
        sd += __shfl_xor(sd, 16, 64);
        sd += __shfl_xor(sd, 32, 64);
        if (cr == 0) {
            float mean = s * (1.f / 512.f);
            float var = ss * (1.f / 512.f) - mean * mean;
            lgs[mh] = (sd - mean * sw) * rsqrtf(var + 1e-5f) + ba2v;
        }
    }
    __syncthreads();
    if (tid < 128) {
        int h = tid & 7;
        float mx = lgs[h];
#pragma unroll
        for (int mm = 1; mm < 16; ++mm) mx = fmaxf(mx, lgs[mm * 8 + h]);
        attn[tid] = __expf(lgs[tid] - mx);
    }
    __syncthreads();
    if (tid < 8) {
        float se = 0.f;
#pragma unroll
        for (int mm = 0; mm < 16; ++mm) se += attn[mm * 8 + tid];
        sinv[tid] = 1.f / se;
    }
    __syncthreads();
    for (int c = tid; c < 640; c += 256) {
        float acc = 0.f;
        int h;
        if (c < 512) {
            h = c >> 6;
            int t = c & 63;
#pragma unroll
            for (int m = 0; m < 16; ++m)
                acc = fmaf(attn[m * 8 + h], b2f(v2b[(size_t)jns[m] * 512 + h * 64 + t]), acc);
        } else {
            int d = c - 512;
            h = d >> 4;
            int t = d & 15;
#pragma unroll
            for (int m = 0; m < 16; ++m)
                acc = fmaf(attn[m * 8 + h], b2f(Es[m * 128 + h * 16 + t]), acc);
        }
        scec[(size_t)n * 640 + c] = f2bf(acc * sinv[h]);
    }
}

// ---------------------------------------------------------------------------
extern "C" void kernel_launch(void* const* d_in, const int* in_sizes, int n_in,
                              void* d_out, int out_size, void* d_ws, size_t ws_size,
                              hipStream_t stream) {
    const float* gene_exp = (const float*)d_in[0];
    const float* token_embs = (const float*)d_in[1];
    const float* coords = (const float*)d_in[2];
    const int* nbr = (const int*)d_in[3];
    const float* w_qkv = (const float*)d_in[4];
    const float* b_qkv = (const float*)d_in[5];
    const float* wa1 = (const float*)d_in[6];
    const float* ba1 = (const float*)d_in[7];
    const float* wa2 = (const float*)d_in[8];
    const float* ba2 = (const float*)d_in[9];
    const float* we1 = (const float*)d_in[10];
    const float* be1 = (const float*)d_in[11];
    const float* we2 = (const float*)d_in[12];
    const float* be2 = (const float*)d_in[13];
    const float* wo1 = (const float*)d_in[14];
    const float* bo1 = (const float*)d_in[15];
    const float* wo2 = (const float*)d_in[16];
    const float* bo2 = (const float*)d_in[17];
    const float* wm1 = (const float*)d_in[18];
    const float* bm1 = (const float*)d_in[19];
    const float* wm2 = (const float*)d_in[20];
    const float* bm2 = (const float*)d_in[21];
    const float* wg1 = (const float*)d_in[22];
    const float* bg1 = (const float*)d_in[23];
    const float* wg2 = (const float*)d_in[24];
    const float* bg2 = (const float*)d_in[25];

    float* out = (float*)d_out;
    float* gene_out = out;             // [2048, 50]
    float* tok_out = out + 2048 * 50;  // [2048, 512]

    float* ws = (float*)d_ws;
    size_t o = 0;
    auto alloc = [&](size_t nf) {
        float* p = ws + o;
        o += nf;
        return p;
    };
    us* x_ln_bf = (us*)alloc((size_t)2048 * 512 / 2);
    us* q2b = (us*)alloc((size_t)16384 * 64 / 2);
    us* k2b = (us*)alloc((size_t)16384 * 64 / 2);
    us* v2b = (us*)alloc((size_t)2048 * 512 / 2);
    us* qpb = (us*)alloc((size_t)16384 * 512 / 2);
    us* kgb = (us*)alloc((size_t)16384 * 512 / 2);
    float* gep = alloc((size_t)2048 * 512);
    us* gepb = (us*)alloc((size_t)2048 * 512 / 2);
    us* edgeb = (us*)alloc(((size_t)2048 * 2048 + 32) / 2);
    us* scec_bf = (us*)alloc((size_t)2048 * 640 / 2);
    float* buf1 = alloc((size_t)2048 * 512);
    us* buf1_bf = (us*)alloc((size_t)2048 * 512 / 2);
    float* buf2 = alloc((size_t)2048 * 2048);
    us* buf2_bf = (us*)alloc((size_t)2048 * 2048 / 2);
    float* tok1 = alloc((size_t)2048 * 512);
    us* tok1_bf = (us*)alloc((size_t)2048 * 512 / 2);
    us* tokout_bf = (us*)alloc((size_t)2048 * 512 / 2);
    us* u_bf = (us*)alloc((size_t)32768 * 128 / 2);
    float* projs = alloc((size_t)32768 * 2);
    float* rns = alloc((size_t)32768);
    us* gene_bf = (us*)alloc((size_t)2048 * 64 / 2);
    float* pk4 = alloc((size_t)4 * 2048 * 512);  // wm2 split-K partials
    us* qkvT = (us*)alloc((size_t)1536 * 512 / 2);
    us* wa1qT = (us*)alloc((size_t)512 * 64 / 2);
    us* wa1kT = (us*)alloc((size_t)512 * 64 / 2);
    us* wa1gT = (us*)alloc((size_t)512 * 64 / 2);
    us* we2T = (us*)alloc((size_t)128 * 128 / 2);
    us* wo1T = (us*)alloc((size_t)512 * 640 / 2);
    us* wo2T = (us*)alloc((size_t)512 * 512 / 2);
    us* wm1T = (us*)alloc((size_t)2048 * 512 / 2);
    us* wm2T = (us*)alloc((size_t)512 * 2048 / 2);
    us* wg1T = (us*)alloc((size_t)512 * 512 / 2);
    us* wg2T = (us*)alloc((size_t)128 * 512 / 2);
    us* wesT = (us*)alloc((size_t)512 * 32 / 2);
    if (o * sizeof(float) > ws_size) return;  // ~136 MB required

    auto mkjob = [](const us* A, const us* Bt, const float* bias, const float* resid,
                    const float* residH, float* outF, us* outB, us* outB2, us* outB3,
                    int M, int Kstride, int nkt, int N, int Nout, int b0) {
        GJob j;
        j.A = A; j.Bt = Bt; j.bias = bias; j.resid = resid; j.residH = residH;
        j.outF = outF; j.outB = outB; j.outB2 = outB2; j.outB3 = outB3;
        j.M = M; j.Kstride = Kstride; j.nkt = nkt; j.N = N; j.Nout = Nout; j.b0 = b0;
        return j;
    };
    auto G1 = [&](const us* A, const us* Bt, const float* bias, const float* resid,
                  const float* residH, float* outF, us* outB, int M, int K, int N,
                  int Nout) {
        GJobs P;
        P.nj = 1;
        P.j[0] = mkjob(A, Bt, bias, resid, residH, outF, outB, nullptr, nullptr,
                       M, K, K >> 6, N, Nout, 0);
        gemm_bf16_kernel<<<(N / 128) * (M / 128), 256, 0, stream>>>(P);
    };

    // 0. weight transpose-casts + wesT + gene cast (one launch)
    hipMemsetAsync(wg2T, 0, (size_t)128 * 512 * 2, stream);  // pad rows 50..127
    {
        TC11 P;
        auto set = [&](int i, const float* s, us* d, int K, int N, int Kld, int& acc) {
            P.j[i] = {s, d, K, N, Kld, acc};
            acc += ((N + 31) / 32) * ((Kld + 31) / 32);
        };
        int acc = 0;
        set(0, w_qkv, qkvT, 512, 1536, 512, acc);
        set(1, wa1, wa1qT, 64, 512, 64, acc);
        set(2, wa1 + 64 * 512, wa1kT, 64, 512, 64, acc);
        set(3, we2, we2T, 128, 128, 128, acc);
        set(4, wo1, wo1T, 640, 512, 640, acc);
        set(5, wo2, wo2T, 512, 512, 512, acc);
        set(6, wm1, wm1T, 512, 2048, 512, acc);
        set(7, wm2, wm2T, 2048, 512, 2048, acc);
        set(8, wg1, wg1T, 512, 512, 512, acc);
        set(9, wa1 + 144 * 512, wa1gT, 50, 512, 64, acc);  // K-padded to 64
        set(10, wg2, wg2T, 512, 50, 512, acc);             // rows 50..127 = memset 0
        P.acc_end = acc;
        P.wa1_s = wa1;
        P.wesT_d = wesT;
        P.gene_s = gene_exp;
        P.gene_d = gene_bf;
        tcast_all<<<acc + 64 + 512, 256, 0, stream>>>(P);
    }

    // 1. LN(token_embs)->bf16 + frame projections (one launch)
    lnproj_kernel<<<2048 + 128, 256, 0, stream>>>(token_embs, x_ln_bf, coords, nbr,
                                                  projs, rns);
    // 2. frame MLP stage 1 -> u_bf
    frame_mlp1_kernel<<<8192, 256, 0, stream>>>(projs, rns, we1, be1, u_bf);
    // 3. BATCH{qkv(split q|k|v), gep, edge}: 192+64+256 = 512 blocks
    {
        GJobs P;
        P.nj = 3;
        P.j[0] = mkjob(x_ln_bf, qkvT, b_qkv, nullptr, nullptr, nullptr, q2b, k2b, v2b,
                       2048, 512, 8, 1536, 1536, 0);
        P.j[1] = mkjob(gene_bf, wa1gT, nullptr, nullptr, nullptr, gep, gepb, nullptr,
                       nullptr, 2048, 64, 1, 512, 512, 192);
        P.j[2] = mkjob(u_bf, we2T, be2, nullptr, nullptr, nullptr, edgeb, nullptr,
                       nullptr, 32768, 128, 2, 128, 128, 256);
        gemm_bf16_kernel<<<512, 256, 0, stream>>>(P);
    }
    // 4. BATCH{qp, kg}: 512+512 = 1024 blocks
    {
        GJobs P;
        P.nj = 2;
        P.j[0] = mkjob(q2b, wa1qT, ba1, nullptr, nullptr, nullptr, qpb, nullptr, nullptr,
                       16384, 64, 1, 512, 512, 0);
        P.j[1] = mkjob(k2b, wa1kT, nullptr, nullptr, gep, nullptr, kgb, nullptr, nullptr,
                       16384, 64, 1, 512, 512, 512);
        gemm_bf16_kernel<<<1024, 256, 0, stream>>>(P);
    }
    // 5. fused logits + softmax + aggregation -> scec bf16
    logits_fused_kernel<<<2048, 256, 0, stream>>>(qpb, kgb, gepb, edgeb, wesT, nbr,
                                                  wa2, ba2, v2b, scec_bf);
    // 6. ctx = mlp2(scec, wo1, wo2); tok1 = token_embs + ctx
    G1(scec_bf, wo1T, bo1, nullptr, nullptr, buf1, nullptr, 2048, 640, 512, 512);
    act_ln_kernel<<<2048, 256, 0, stream>>>(nullptr, buf1_bf, buf1, 512, 1);
    G1(buf1_bf, wo2T, bo2, token_embs, nullptr, tok1, tok1_bf, 2048, 512, 512, 512);
    // 7. tok2 = tok1 + mlp2(tok1, wm1, wm2) -> d_out tok section
    G1(tok1_bf, wm1T, bm1, nullptr, nullptr, buf2, nullptr, 2048, 512, 2048, 2048);
    act_ln_kernel<<<2048, 256, 0, stream>>>(nullptr, buf2_bf, buf2, 2048, 1);
    {
        // wm2 split-K=4 as one batched launch (4x64 = 256 blocks), fp32 partials
        GJobs P;
        P.nj = 4;
#pragma unroll
        for (int s = 0; s < 4; ++s)
            P.j[s] = mkjob(buf2_bf + s * 512, wm2T + s * 512, nullptr, nullptr, nullptr,
                           pk4 + (size_t)s * 2048 * 512, nullptr, nullptr, nullptr,
                           2048, 2048, 8, 512, 512, s * 64);
        gemm_bf16_kernel<<<256, 256, 0, stream>>>(P);
        wm2_combine<<<4096, 256, 0, stream>>>(pk4, bm2, tok1, tok_out, tokout_bf);
    }
    // 8. gene_out = mlp2(tok2, wg1, wg2)
    G1(tokout_bf, wg1T, bg1, nullptr, nullptr, buf1, nullptr, 2048, 512, 512, 512);
    act_ln_kernel<<<2048, 256, 0, stream>>>(nullptr, buf1_bf, buf1, 512, 1);
    G1(buf1_bf, wg2T, bg2, nullptr, nullptr, gene_out, nullptr, 2048, 512, 128, 50);
}